// Round 4
// baseline (792.312 us; speedup 1.0000x reference)
//
#include <hip/hip_runtime.h>

#define NN 50000
#define NE 400000
#define NB 128
#define NINF (-__builtin_inff())

// ============================ CSR build ============================
__global__ __launch_bounds__(256) void k_hist(const int* __restrict__ dstv, int* __restrict__ deg) {
    int e = blockIdx.x * 256 + threadIdx.x;
    if (e < NE) atomicAdd(&deg[dstv[e]], 1);
}

__global__ __launch_bounds__(1024) void k_scan(const int* __restrict__ deg, int* __restrict__ rowptr) {
    __shared__ int wsum[16];
    __shared__ int total_s;
    const int tid = threadIdx.x, lane = tid & 63, w = tid >> 6;
    if (tid == 0) rowptr[0] = 0;
    int carry = 0;
    for (int base = 0; base < NN; base += 1024) {
        int i = base + tid;
        int v = (i < NN) ? deg[i] : 0;
        int incl = v;
        #pragma unroll
        for (int off = 1; off < 64; off <<= 1) {
            int t = __shfl_up(incl, off);
            if (lane >= off) incl += t;
        }
        if (lane == 63) wsum[w] = incl;
        __syncthreads();
        if (tid < 16) {
            int s = wsum[tid];
            int si = s;
            #pragma unroll
            for (int off = 1; off < 16; off <<= 1) {
                int t = __shfl_up(si, off, 16);
                if (tid >= off) si += t;
            }
            wsum[tid] = si - s;
            if (tid == 15) total_s = si;
        }
        __syncthreads();
        if (i < NN) rowptr[i + 1] = carry + wsum[w] + incl;
        carry += total_s;
        __syncthreads();
    }
}

__global__ __launch_bounds__(256) void k_scatter(const int* __restrict__ dstv, const int* __restrict__ rowptr,
                                                 int* __restrict__ cnt, int* __restrict__ eid) {
    int e = blockIdx.x * 256 + threadIdx.x;
    if (e < NE) {
        int d = dstv[e];
        int pos = rowptr[d] + atomicAdd(&cnt[d], 1);
        eid[pos] = e;
    }
}

__global__ __launch_bounds__(256) void k_permute(const int* __restrict__ eid, const int* __restrict__ srcv,
                                                 const float* __restrict__ eattr, int* __restrict__ src_perm,
                                                 float4* __restrict__ ea_perm) {
    int p = blockIdx.x * 256 + threadIdx.x;
    if (p < NE) {
        int e = eid[p];
        src_perm[p] = srcv[e];
        ea_perm[p * 2] = ((const float4*)eattr)[e * 2];
        ea_perm[p * 2 + 1] = ((const float4*)eattr)[e * 2 + 1];
    }
}

// ============================ GEMM: [N,64] @ [64,256] -> xl / xr ============================
// block: 64 rows x 128 cols; A (16KB) and W (32KB) both LDS-staged.
// blockIdx.y: bit0 = col half, bit1 = which W. BN folded: W*=sc, acc init = (sh@W)[col].
__global__ __launch_bounds__(256) void k_gemm64(const float* __restrict__ A, const float* __restrict__ Wl,
                                                const float* __restrict__ Wr, float* __restrict__ Cl,
                                                float* __restrict__ Cr, const float* __restrict__ bnp) {
    __shared__ float As[64 * 64];  // 16KB
    __shared__ float Ws[64 * 128]; // 32KB
    const int tid = threadIdx.x;
    const int mat = blockIdx.y >> 1, ch = blockIdx.y & 1;
    const float* W = mat ? Wr : Wl;
    float* C = mat ? Cr : Cl;
    const int r0b = blockIdx.x * 64;

    for (int i = tid; i < 2048; i += 256) {
        const int k = i >> 5, c4 = i & 31;
        float4 v = ((const float4*)W)[k * 64 + ch * 32 + c4];
        if (bnp) {
            const float s = bnp[128 + k];
            v.x *= s; v.y *= s; v.z *= s; v.w *= s;
        }
        ((float4*)Ws)[i] = v;
    }
    for (int i = tid; i < 1024; i += 256) {
        const int r = i >> 4, c4 = i & 15;
        const int rg = (r0b + r < NN) ? (r0b + r) : (NN - 1);
        ((float4*)As)[i] = ((const float4*)A)[rg * 16 + c4];
    }
    __syncthreads();

    const int cg = tid & 31; // cols ch*128 + cg*4 ..+3
    const int rq = tid >> 5; // rows rq*8..+7
    float acc[8][4];
    if (bnp) {
        const float* shW = bnp + 256 + mat * 256 + ch * 128 + cg * 4;
        #pragma unroll
        for (int rr = 0; rr < 8; ++rr) {
            acc[rr][0] = shW[0]; acc[rr][1] = shW[1]; acc[rr][2] = shW[2]; acc[rr][3] = shW[3];
        }
    } else {
        #pragma unroll
        for (int rr = 0; rr < 8; ++rr)
            acc[rr][0] = acc[rr][1] = acc[rr][2] = acc[rr][3] = 0.f;
    }

    for (int kq = 0; kq < 16; ++kq) {
        float4 av[8];
        #pragma unroll
        for (int rr = 0; rr < 8; ++rr)
            av[rr] = ((const float4*)As)[(rq * 8 + rr) * 16 + kq];
        #pragma unroll
        for (int kk = 0; kk < 4; ++kk) {
            const float4 w = *(const float4*)(Ws + ((kq * 4 + kk) << 7) + (cg << 2));
            #pragma unroll
            for (int rr = 0; rr < 8; ++rr) {
                const float a = reinterpret_cast<const float*>(&av[rr])[kk];
                acc[rr][0] = fmaf(a, w.x, acc[rr][0]);
                acc[rr][1] = fmaf(a, w.y, acc[rr][1]);
                acc[rr][2] = fmaf(a, w.z, acc[rr][2]);
                acc[rr][3] = fmaf(a, w.w, acc[rr][3]);
            }
        }
    }
    #pragma unroll
    for (int rr = 0; rr < 8; ++rr) {
        const int r = r0b + rq * 8 + rr;
        if (r < NN)
            *(float4*)(C + (size_t)r * 256 + ch * 128 + cg * 4) =
                make_float4(acc[rr][0], acc[rr][1], acc[rr][2], acc[rr][3]);
    }
}

// ============================ Fused edge kernel ============================
// wave per node; lane L owns channels 4L..4L+3; We in 32 regs; unroll-4 slot pipeline,
// dual online-softmax chains (even/odd edges) merged per node.
template <bool PERM>
__global__ __launch_bounds__(256, 4) void k_agg(const float* __restrict__ xl, float* __restrict__ xragg,
                                                const float* __restrict__ att, const float* __restrict__ gatb,
                                                const int* __restrict__ rowptr, const int* __restrict__ eid,
                                                const int* __restrict__ srcv, const float* __restrict__ eattr,
                                                const int* __restrict__ src_perm, const float4* __restrict__ ea_perm,
                                                const float* __restrict__ We) {
    const int lane = threadIdx.x & 63;
    const float4 we0 = ((const float4*)(We + 0 * 256))[lane];
    const float4 we1 = ((const float4*)(We + 1 * 256))[lane];
    const float4 we2 = ((const float4*)(We + 2 * 256))[lane];
    const float4 we3 = ((const float4*)(We + 3 * 256))[lane];
    const float4 we4 = ((const float4*)(We + 4 * 256))[lane];
    const float4 we5 = ((const float4*)(We + 5 * 256))[lane];
    const float4 we6 = ((const float4*)(We + 6 * 256))[lane];
    const float4 we7 = ((const float4*)(We + 7 * 256))[lane];
    const float4 attf = ((const float4*)att)[lane];
    const float4 gbf = ((const float4*)gatb)[lane];
    const int nw = gridDim.x * (blockDim.x >> 6);
    int wid = blockIdx.x * (blockDim.x >> 6) + (threadIdx.x >> 6);

#define LOADE(X, idx)                                                          \
    {                                                                          \
        int s_;                                                                \
        const float4* eap_;                                                    \
        if (PERM) {                                                            \
            s_ = src_perm[idx];                                                \
            eap_ = ea_perm + (size_t)(idx) * 2;                                \
        } else {                                                               \
            const int e_ = eid[idx];                                           \
            s_ = srcv[e_];                                                     \
            eap_ = (const float4*)(eattr + (size_t)e_ * 8);                    \
        }                                                                      \
        X##x = ((const float4*)(xl + (size_t)s_ * 256))[lane];                 \
        X##a = eap_[0];                                                        \
        X##b = eap_[1];                                                        \
    }

#define PROC(X, M, D, C0, C1, C2, C3)                                          \
    {                                                                          \
        float v0 = fmaf(X##a.x, we0.x, xr.x), v1 = fmaf(X##a.x, we0.y, xr.y);  \
        float v2 = fmaf(X##a.x, we0.z, xr.z), v3 = fmaf(X##a.x, we0.w, xr.w);  \
        v0 = fmaf(X##a.y, we1.x, v0); v1 = fmaf(X##a.y, we1.y, v1);            \
        v2 = fmaf(X##a.y, we1.z, v2); v3 = fmaf(X##a.y, we1.w, v3);            \
        v0 = fmaf(X##a.z, we2.x, v0); v1 = fmaf(X##a.z, we2.y, v1);            \
        v2 = fmaf(X##a.z, we2.z, v2); v3 = fmaf(X##a.z, we2.w, v3);            \
        v0 = fmaf(X##a.w, we3.x, v0); v1 = fmaf(X##a.w, we3.y, v1);            \
        v2 = fmaf(X##a.w, we3.z, v2); v3 = fmaf(X##a.w, we3.w, v3);            \
        v0 = fmaf(X##b.x, we4.x, v0); v1 = fmaf(X##b.x, we4.y, v1);            \
        v2 = fmaf(X##b.x, we4.z, v2); v3 = fmaf(X##b.x, we4.w, v3);            \
        v0 = fmaf(X##b.y, we5.x, v0); v1 = fmaf(X##b.y, we5.y, v1);            \
        v2 = fmaf(X##b.y, we5.z, v2); v3 = fmaf(X##b.y, we5.w, v3);            \
        v0 = fmaf(X##b.z, we6.x, v0); v1 = fmaf(X##b.z, we6.y, v1);            \
        v2 = fmaf(X##b.z, we6.z, v2); v3 = fmaf(X##b.z, we6.w, v3);            \
        v0 = fmaf(X##b.w, we7.x, v0); v1 = fmaf(X##b.w, we7.y, v1);            \
        v2 = fmaf(X##b.w, we7.z, v2); v3 = fmaf(X##b.w, we7.w, v3);            \
        v0 += X##x.x; v1 += X##x.y; v2 += X##x.z; v3 += X##x.w;                \
        v0 = fmaxf(v0, 0.2f * v0); v1 = fmaxf(v1, 0.2f * v1);                  \
        v2 = fmaxf(v2, 0.2f * v2); v3 = fmaxf(v3, 0.2f * v3);                  \
        float part = v0 * attf.x;                                              \
        part = fmaf(v1, attf.y, part);                                         \
        part = fmaf(v2, attf.z, part);                                         \
        part = fmaf(v3, attf.w, part);                                         \
        part += __shfl_xor(part, 1);                                           \
        part += __shfl_xor(part, 2);                                           \
        part += __shfl_xor(part, 4);                                           \
        part += __shfl_xor(part, 8);                                           \
        const float mn = fmaxf(M, part);                                       \
        const float scl = __expf(M - mn);                                      \
        const float p = __expf(part - mn);                                     \
        D = fmaf(D, scl, p);                                                   \
        C0 = fmaf(C0, scl, p * X##x.x);                                        \
        C1 = fmaf(C1, scl, p * X##x.y);                                        \
        C2 = fmaf(C2, scl, p * X##x.z);                                        \
        C3 = fmaf(C3, scl, p * X##x.w);                                        \
        M = mn;                                                                \
    }

    for (int n = wid; n < NN; n += nw) {
        const int e0 = rowptr[n], e1 = rowptr[n + 1];
        const float4 xr = ((const float4*)(xragg + (size_t)n * 256))[lane];
        float mA = NINF, dA = 0.f, cA0 = 0.f, cA1 = 0.f, cA2 = 0.f, cA3 = 0.f;
        float mB = NINF, dB = 0.f, cB0 = 0.f, cB1 = 0.f, cB2 = 0.f, cB3 = 0.f;
        float4 Ax, Aa, Ab, Bx, Ba, Bb;
        if (e0 < e1) LOADE(A, e0);
        if (e0 + 1 < e1) LOADE(B, e0 + 1);
        int i = e0;
        for (; i + 5 < e1; i += 4) {
            float4 Cx, Ca, Cb, Dx, Da, Db;
            LOADE(C, i + 2);
            LOADE(D, i + 3);
            PROC(A, mA, dA, cA0, cA1, cA2, cA3);
            PROC(B, mB, dB, cB0, cB1, cB2, cB3);
            LOADE(A, i + 4);
            LOADE(B, i + 5);
            PROC(C, mA, dA, cA0, cA1, cA2, cA3);
            PROC(D, mB, dB, cB0, cB1, cB2, cB3);
        }
        if (i < e1) PROC(A, mA, dA, cA0, cA1, cA2, cA3);
        if (i + 1 < e1) PROC(B, mB, dB, cB0, cB1, cB2, cB3);
        for (int j = i + 2; j < e1; ++j) {
            LOADE(A, j);
            PROC(A, mA, dA, cA0, cA1, cA2, cA3);
        }
        float4 o;
        if (e1 > e0) {
            const float m = fmaxf(mA, mB);
            const float wA = __expf(mA - m), wB = __expf(mB - m);
            const float inv = 1.0f / fmaf(wA, dA, wB * dB);
            o.x = fmaf((wA * cA0 + wB * cB0), inv, gbf.x);
            o.y = fmaf((wA * cA1 + wB * cB1), inv, gbf.y);
            o.z = fmaf((wA * cA2 + wB * cB2), inv, gbf.z);
            o.w = fmaf((wA * cA3 + wB * cB3), inv, gbf.w);
        } else {
            o = gbf;
        }
        ((float4*)(xragg + (size_t)n * 256))[lane] = o;
    }
#undef LOADE
#undef PROC
}

// ============================ tr GEMM: [N,256]@[256,64] + bias, relu, BN stats ============================
// block: 64 rows x 64 cols; A chunk (padded, 17KB) + W chunk (16KB) LDS-staged; K chunked x4.
__global__ __launch_bounds__(256) void k_tr(const float* __restrict__ A, const float* __restrict__ W,
                                            const float* __restrict__ bias, float* __restrict__ Hout,
                                            float* __restrict__ stats) {
    __shared__ float As[64 * 68]; // padded rows: 17,408 B
    __shared__ float Ws[64 * 64]; // 16KB
    __shared__ float red[128];
    const int tid = threadIdx.x;
    const int cg = tid & 15; // cols cg*4..+3
    const int rq = tid >> 4; // rows rq*4..+3
    const int r0b = blockIdx.x * 64;

    float acc[4][4];
    {
        const float b0 = bias[cg * 4], b1 = bias[cg * 4 + 1], b2 = bias[cg * 4 + 2], b3 = bias[cg * 4 + 3];
        #pragma unroll
        for (int rr = 0; rr < 4; ++rr) { acc[rr][0] = b0; acc[rr][1] = b1; acc[rr][2] = b2; acc[rr][3] = b3; }
    }

    for (int kc = 0; kc < 4; ++kc) {
        if (kc) __syncthreads();
        for (int i = tid; i < 1024; i += 256)
            ((float4*)Ws)[i] = ((const float4*)(W + kc * 4096))[i];
        for (int i = tid; i < 1024; i += 256) {
            const int r = i >> 4, c4 = i & 15;
            const int rg = (r0b + r < NN) ? (r0b + r) : (NN - 1);
            *(float4*)(As + r * 68 + c4 * 4) = ((const float4*)A)[(size_t)rg * 64 + kc * 16 + c4];
        }
        __syncthreads();
        for (int kq = 0; kq < 16; ++kq) {
            float4 av[4];
            #pragma unroll
            for (int rr = 0; rr < 4; ++rr)
                av[rr] = *(const float4*)(As + (rq * 4 + rr) * 68 + kq * 4);
            #pragma unroll
            for (int kk = 0; kk < 4; ++kk) {
                const float4 w = *(const float4*)(Ws + ((kq * 4 + kk) << 6) + (cg << 2));
                #pragma unroll
                for (int rr = 0; rr < 4; ++rr) {
                    const float a = reinterpret_cast<const float*>(&av[rr])[kk];
                    acc[rr][0] = fmaf(a, w.x, acc[rr][0]);
                    acc[rr][1] = fmaf(a, w.y, acc[rr][1]);
                    acc[rr][2] = fmaf(a, w.z, acc[rr][2]);
                    acc[rr][3] = fmaf(a, w.w, acc[rr][3]);
                }
            }
        }
    }
    float lsum[4] = {0.f, 0.f, 0.f, 0.f}, lsq[4] = {0.f, 0.f, 0.f, 0.f};
    #pragma unroll
    for (int rr = 0; rr < 4; ++rr) {
        const int r = r0b + rq * 4 + rr;
        if (r < NN) {
            float v0 = fmaxf(acc[rr][0], 0.f), v1 = fmaxf(acc[rr][1], 0.f);
            float v2 = fmaxf(acc[rr][2], 0.f), v3 = fmaxf(acc[rr][3], 0.f);
            lsum[0] += v0; lsum[1] += v1; lsum[2] += v2; lsum[3] += v3;
            lsq[0] = fmaf(v0, v0, lsq[0]); lsq[1] = fmaf(v1, v1, lsq[1]);
            lsq[2] = fmaf(v2, v2, lsq[2]); lsq[3] = fmaf(v3, v3, lsq[3]);
            *(float4*)(Hout + (size_t)r * 64 + cg * 4) = make_float4(v0, v1, v2, v3);
        }
    }
    __syncthreads();
    if (tid < 128) red[tid] = 0.f;
    __syncthreads();
    #pragma unroll
    for (int j = 0; j < 4; ++j) {
        atomicAdd(&red[cg * 4 + j], lsum[j]);
        atomicAdd(&red[64 + cg * 4 + j], lsq[j]);
    }
    __syncthreads();
    if (tid < 64) {
        atomicAdd(&stats[tid], red[tid]);
        atomicAdd(&stats[64 + tid], red[64 + tid]);
    }
}

// stats layout per layer (stride 768): [0:64] sum, [64:128] sumsq, [128:192] sc,
// [192:256] sh, [256:512] sh@Wl_next, [512:768] sh@Wr_next
__global__ __launch_bounds__(256) void k_bn_finalize(float* __restrict__ st, const float* __restrict__ g,
                                                     const float* __restrict__ b, const float* __restrict__ Wln,
                                                     const float* __restrict__ Wrn) {
    __shared__ float sh_s[64];
    const int tid = threadIdx.x;
    if (tid < 64) {
        const float mu = st[tid] * (1.0f / (float)NN);
        const float var = st[64 + tid] * (1.0f / (float)NN) - mu * mu;
        const float rstd = rsqrtf(var + 1e-5f);
        const float sc = g[tid] * rstd;
        const float sh = fmaf(-mu, sc, b[tid]);
        st[128 + tid] = sc;
        st[192 + tid] = sh;
        sh_s[tid] = sh;
    }
    __syncthreads();
    if (Wln) {
        float al = 0.f, ar = 0.f;
        for (int k = 0; k < 64; ++k) {
            al = fmaf(sh_s[k], Wln[k * 256 + tid], al);
            ar = fmaf(sh_s[k], Wrn[k * 256 + tid], ar);
        }
        st[256 + tid] = al;
        st[512 + tid] = ar;
    }
}

// ============================ fused gate + pool (+ final BN fold) ============================
__global__ __launch_bounds__(256) void k_pool(const float* __restrict__ h, const float* __restrict__ gw,
                                              const int* __restrict__ bidx, const float* __restrict__ st,
                                              float* __restrict__ pooled) {
    __shared__ float gate_s[1024];
    __shared__ float red[4];
    __shared__ float pp[4][64];
    const int b = blockIdx.x, tid = threadIdx.x, lane = tid & 63, w = tid >> 6;
    int lo = 0, hi = NN;
    while (lo < hi) { int mid = (lo + hi) >> 1; if (bidx[mid] < b) lo = mid + 1; else hi = mid; }
    const int s0 = lo;
    lo = 0; hi = NN;
    while (lo < hi) { int mid = (lo + hi) >> 1; if (bidx[mid] < b + 1) lo = mid + 1; else hi = mid; }
    const int s1 = lo;
    const int seg = s1 - s0;
    if (seg == 0) {
        if (tid < 64) pooled[b * 64 + tid] = st[192 + tid];
        return;
    }
    const float gwv = gw[lane] * st[128 + lane];
    for (int i = s0 + w; i < s1; i += 4) {
        float p = h[(size_t)i * 64 + lane] * gwv;
        #pragma unroll
        for (int off = 32; off; off >>= 1) p += __shfl_xor(p, off);
        if (lane == 0) gate_s[i - s0] = p;
    }
    __syncthreads();
    float v = NINF;
    for (int i = tid; i < seg; i += 256) v = fmaxf(v, gate_s[i]);
    #pragma unroll
    for (int off = 32; off; off >>= 1) v = fmaxf(v, __shfl_xor(v, off));
    if (lane == 0) red[w] = v;
    __syncthreads();
    const float mx = fmaxf(fmaxf(red[0], red[1]), fmaxf(red[2], red[3]));
    __syncthreads();
    float d = 0.f;
    for (int i = tid; i < seg; i += 256) {
        const float ex = __expf(gate_s[i] - mx);
        gate_s[i] = ex;
        d += ex;
    }
    #pragma unroll
    for (int off = 32; off; off >>= 1) d += __shfl_xor(d, off);
    if (lane == 0) red[w] = d;
    __syncthreads();
    const float den = red[0] + red[1] + red[2] + red[3];
    const int c = tid & 63, ro = tid >> 6;
    float acc = 0.f;
    for (int i = s0 + ro; i < s1; i += 4) acc = fmaf(gate_s[i - s0], h[(size_t)i * 64 + c], acc);
    pp[ro][c] = acc;
    __syncthreads();
    if (ro == 0) {
        const float raw = (pp[0][c] + pp[1][c] + pp[2][c] + pp[3][c]) / den;
        pooled[b * 64 + c] = fmaf(raw, st[128 + c], st[192 + c]);
    }
}

// ============================ MLP head ============================
__global__ __launch_bounds__(256) void k_head(const float* __restrict__ pooled, const float* __restrict__ fc,
                                              const float* __restrict__ nrot, const float* __restrict__ W1,
                                              const float* __restrict__ b1, const float* __restrict__ W2,
                                              const float* __restrict__ b2, const float* __restrict__ W3,
                                              const float* __restrict__ b3, const float* __restrict__ W4,
                                              const float* __restrict__ b4, float* __restrict__ out) {
    __shared__ float z[66], a1[256], a2[128], a3[64];
    const int b = blockIdx.x, tid = threadIdx.x;
    if (tid < 64) z[tid] = pooled[b * 64 + tid];
    if (tid == 64) z[64] = fc[b];
    if (tid == 65) z[65] = nrot[b];
    __syncthreads();
    float s = b1[tid];
    for (int k = 0; k < 66; ++k) s = fmaf(z[k], W1[k * 256 + tid], s);
    a1[tid] = fmaxf(s, 0.f);
    __syncthreads();
    if (tid < 128) {
        float s2 = b2[tid];
        for (int k = 0; k < 256; ++k) s2 = fmaf(a1[k], W2[k * 128 + tid], s2);
        a2[tid] = fmaxf(s2, 0.f);
    }
    __syncthreads();
    if (tid < 64) {
        float s3 = b3[tid];
        for (int k = 0; k < 128; ++k) s3 = fmaf(a2[k], W3[k * 64 + tid], s3);
        a3[tid] = fmaxf(s3, 0.f);
    }
    __syncthreads();
    if (tid < 64) {
        float p = a3[tid] * W4[tid];
        #pragma unroll
        for (int off = 32; off; off >>= 1) p += __shfl_xor(p, off);
        if (tid == 0) out[b] = p + b4[0];
    }
}

// ============================ launch ============================
extern "C" void kernel_launch(void* const* d_in, const int* in_sizes, int n_in,
                              void* d_out, int out_size, void* d_ws, size_t ws_size,
                              hipStream_t stream) {
    const float* x     = (const float*)d_in[0];
    const int*   ei    = (const int*)d_in[1];
    const float* eattr = (const float*)d_in[2];
    const float* fcv   = (const float*)d_in[3];
    const float* nrot  = (const float*)d_in[4];
    const int*   bidx  = (const int*)d_in[5];
    const float* Wl    = (const float*)d_in[6];
    const float* Wr    = (const float*)d_in[7];
    const float* We    = (const float*)d_in[8];
    const float* att   = (const float*)d_in[9];
    const float* gatb  = (const float*)d_in[10];
    const float* trW   = (const float*)d_in[11];
    const float* trb   = (const float*)d_in[12];
    const float* bng   = (const float*)d_in[13];
    const float* bnb   = (const float*)d_in[14];
    const float* gateW = (const float*)d_in[15];
    const float* W1    = (const float*)d_in[17];
    const float* b1    = (const float*)d_in[18];
    const float* W2    = (const float*)d_in[19];
    const float* b2    = (const float*)d_in[20];
    const float* W3    = (const float*)d_in[21];
    const float* b3    = (const float*)d_in[22];
    const float* W4    = (const float*)d_in[23];
    const float* b4    = (const float*)d_in[24];
    float* out = (float*)d_out;

    const int* srcv = ei;
    const int* dstv = ei + NE;

    char* w = (char*)d_ws;
    float*  xl       = (float*)(w);                 // 51,200,000
    float*  xragg    = (float*)(w + 51200000);      // 51,200,000 (xr in, agg out)
    float*  hbuf     = (float*)(w + 102400000);     // 12,800,000
    int*    deg      = (int*)  (w + 102400000);     // overlaps hbuf (dead before first k_tr)
    int*    cnt      = (int*)  (w + 102600000);     // overlaps hbuf
    int*    eid      = (int*)  (w + 115200000);     // 1,600,000
    int*    rowptr   = (int*)  (w + 116800000);     // 200,004
    float*  stats    = (float*)(w + 117000064);     // 9,216 (3 * 768 * 4)
    float*  pooled   = (float*)(w + 117009280);     // 32,768 -> 117,042,048
    int*    src_perm = (int*)  (w + 117042048);     // 1,600,000
    float4* ea_perm  = (float4*)(w + 118642048);    // 12,800,000 -> 131,442,048
    const bool use_perm = (ws_size >= (size_t)131442048);

    hipMemsetAsync(deg, 0, 400000, stream);         // deg + cnt
    hipMemsetAsync(stats, 0, 9216, stream);
    k_hist<<<(NE + 255) / 256, 256, 0, stream>>>(dstv, deg);
    k_scan<<<1, 1024, 0, stream>>>(deg, rowptr);
    k_scatter<<<(NE + 255) / 256, 256, 0, stream>>>(dstv, rowptr, cnt, eid);
    if (use_perm)
        k_permute<<<(NE + 255) / 256, 256, 0, stream>>>(eid, srcv, eattr, src_perm, ea_perm);

    const float* hin = x;
    for (int l = 0; l < 3; ++l) {
        const float* bnp = (l == 0) ? nullptr : (stats + (l - 1) * 768);
        dim3 gg((NN + 63) / 64, 4);
        k_gemm64<<<gg, 256, 0, stream>>>(hin, Wl + l * 16384, Wr + l * 16384, xl, xragg, bnp);
        if (use_perm)
            k_agg<true><<<2048, 256, 0, stream>>>(xl, xragg, att + l * 256, gatb + l * 256, rowptr,
                                                  eid, srcv, eattr, src_perm, ea_perm, We + l * 2048);
        else
            k_agg<false><<<2048, 256, 0, stream>>>(xl, xragg, att + l * 256, gatb + l * 256, rowptr,
                                                   eid, srcv, eattr, src_perm, ea_perm, We + l * 2048);
        k_tr<<<(NN + 63) / 64, 256, 0, stream>>>(xragg, trW + l * 16384, trb + l * 64, hbuf, stats + l * 768);
        k_bn_finalize<<<1, 256, 0, stream>>>(stats + l * 768, bng + l * 64, bnb + l * 64,
                                             (l < 2) ? (Wl + (l + 1) * 16384) : nullptr,
                                             (l < 2) ? (Wr + (l + 1) * 16384) : nullptr);
        hin = hbuf;
    }
    k_pool<<<NB, 256, 0, stream>>>(hbuf, gateW, bidx, stats + 2 * 768, pooled);
    k_head<<<NB, 256, 0, stream>>>(pooled, fcv, nrot, W1, b1, W2, b2, W3, b3, W4, b4, out);
}

// Round 5
// 759.465 us; speedup vs baseline: 1.0433x; 1.0433x over previous
//
#include <hip/hip_runtime.h>

#define NN 50000
#define NE 400000
#define NB 128
#define NINF (-__builtin_inff())

__device__ __forceinline__ float dpp_add16(float x) {
    // sum over each 16-lane row (head group): xor 1,2,4,8 via row-local DPP, VALU-only
    int v = __float_as_int(x);
    x += __int_as_float(__builtin_amdgcn_update_dpp(0, v, 0xB1, 0xF, 0xF, true));  // quad_perm(1,0,3,2)
    v = __float_as_int(x);
    x += __int_as_float(__builtin_amdgcn_update_dpp(0, v, 0x4E, 0xF, 0xF, true));  // quad_perm(2,3,0,1)
    v = __float_as_int(x);
    x += __int_as_float(__builtin_amdgcn_update_dpp(0, v, 0x141, 0xF, 0xF, true)); // row_half_mirror
    v = __float_as_int(x);
    x += __int_as_float(__builtin_amdgcn_update_dpp(0, v, 0x140, 0xF, 0xF, true)); // row_mirror
    return x;
}

// ============================ CSR build ============================
__global__ __launch_bounds__(256) void k_hist(const int* __restrict__ dstv, int* __restrict__ deg) {
    int e = blockIdx.x * 256 + threadIdx.x;
    if (e < NE) atomicAdd(&deg[dstv[e]], 1);
}

__global__ __launch_bounds__(1024) void k_scan(const int* __restrict__ deg, int* __restrict__ rowptr) {
    __shared__ int wsum[16];
    __shared__ int total_s;
    const int tid = threadIdx.x, lane = tid & 63, w = tid >> 6;
    if (tid == 0) rowptr[0] = 0;
    int carry = 0;
    for (int base = 0; base < NN; base += 1024) {
        int i = base + tid;
        int v = (i < NN) ? deg[i] : 0;
        int incl = v;
        #pragma unroll
        for (int off = 1; off < 64; off <<= 1) {
            int t = __shfl_up(incl, off);
            if (lane >= off) incl += t;
        }
        if (lane == 63) wsum[w] = incl;
        __syncthreads();
        if (tid < 16) {
            int s = wsum[tid];
            int si = s;
            #pragma unroll
            for (int off = 1; off < 16; off <<= 1) {
                int t = __shfl_up(si, off, 16);
                if (tid >= off) si += t;
            }
            wsum[tid] = si - s;
            if (tid == 15) total_s = si;
        }
        __syncthreads();
        if (i < NN) rowptr[i + 1] = carry + wsum[w] + incl;
        carry += total_s;
        __syncthreads();
    }
}

// scatter + permute fused: writes CSR-ordered src / edge_attr directly
__global__ __launch_bounds__(256) void k_scatter(const int* __restrict__ dstv, const int* __restrict__ srcv,
                                                 const float* __restrict__ eattr, const int* __restrict__ rowptr,
                                                 int* __restrict__ cnt, int* __restrict__ eid,
                                                 int* __restrict__ src_perm, float4* __restrict__ ea_perm,
                                                 int use_perm) {
    int e = blockIdx.x * 256 + threadIdx.x;
    if (e < NE) {
        int d = dstv[e];
        int pos = rowptr[d] + atomicAdd(&cnt[d], 1);
        eid[pos] = e;
        if (use_perm) {
            src_perm[pos] = srcv[e];
            ea_perm[(size_t)pos * 2] = ((const float4*)eattr)[e * 2];
            ea_perm[(size_t)pos * 2 + 1] = ((const float4*)eattr)[e * 2 + 1];
        }
    }
}

// ============================ GEMM: [N,64] @ [64,256] -> xl / xr ============================
// block: 64 rows x 128 cols; A (16KB) + W (32KB) LDS-staged. blockIdx.y: bit0 = col half, bit1 = mat.
// BN of prev layer computed IN-KERNEL from raw stats: W_staged = diag(sc)*W, acc init = (sh @ W)[col].
__global__ __launch_bounds__(256) void k_gemm64(const float* __restrict__ A, const float* __restrict__ Wl,
                                                const float* __restrict__ Wr, float* __restrict__ Cl,
                                                float* __restrict__ Cr, const float* __restrict__ stats,
                                                const float* __restrict__ bg, const float* __restrict__ bb) {
    __shared__ float As[64 * 64];  // 16KB
    __shared__ float Ws[64 * 128]; // 32KB
    __shared__ float sc_s[64], sh_s[64], shW_s[128];
    const int tid = threadIdx.x;
    const int mat = blockIdx.y >> 1, ch = blockIdx.y & 1;
    const float* W = mat ? Wr : Wl;
    float* C = mat ? Cr : Cl;
    const int r0b = blockIdx.x * 64;

    if (stats) {
        if (tid < 64) {
            const float mu = stats[tid] * (1.0f / (float)NN);
            const float var = stats[64 + tid] * (1.0f / (float)NN) - mu * mu;
            const float rstd = rsqrtf(var + 1e-5f);
            const float sc = bg[tid] * rstd;
            sc_s[tid] = sc;
            sh_s[tid] = fmaf(-mu, sc, bb[tid]);
        }
        __syncthreads();
    }
    for (int i = tid; i < 2048; i += 256) {
        const int k = i >> 5, c4 = i & 31;
        float4 v = ((const float4*)W)[k * 64 + ch * 32 + c4];
        if (stats) {
            const float s = sc_s[k];
            v.x *= s; v.y *= s; v.z *= s; v.w *= s;
        }
        ((float4*)Ws)[i] = v;
    }
    for (int i = tid; i < 1024; i += 256) {
        const int r = i >> 4, c4 = i & 15;
        const int rg = (r0b + r < NN) ? (r0b + r) : (NN - 1);
        ((float4*)As)[i] = ((const float4*)A)[rg * 16 + c4];
    }
    if (stats && tid < 128) {
        const float* wc = W + ch * 128 + tid;
        float s = 0.f;
        for (int k = 0; k < 64; ++k) s = fmaf(sh_s[k], wc[k * 256], s);
        shW_s[tid] = s;
    }
    __syncthreads();

    const int cg = tid & 31; // cols ch*128 + cg*4 ..+3
    const int rq = tid >> 5; // rows rq*8..+7
    float acc[8][4];
    if (stats) {
        #pragma unroll
        for (int rr = 0; rr < 8; ++rr) {
            acc[rr][0] = shW_s[cg * 4]; acc[rr][1] = shW_s[cg * 4 + 1];
            acc[rr][2] = shW_s[cg * 4 + 2]; acc[rr][3] = shW_s[cg * 4 + 3];
        }
    } else {
        #pragma unroll
        for (int rr = 0; rr < 8; ++rr)
            acc[rr][0] = acc[rr][1] = acc[rr][2] = acc[rr][3] = 0.f;
    }

    for (int kq = 0; kq < 16; ++kq) {
        float4 av[8];
        #pragma unroll
        for (int rr = 0; rr < 8; ++rr)
            av[rr] = ((const float4*)As)[(rq * 8 + rr) * 16 + kq];
        #pragma unroll
        for (int kk = 0; kk < 4; ++kk) {
            const float4 w = *(const float4*)(Ws + ((kq * 4 + kk) << 7) + (cg << 2));
            #pragma unroll
            for (int rr = 0; rr < 8; ++rr) {
                const float a = reinterpret_cast<const float*>(&av[rr])[kk];
                acc[rr][0] = fmaf(a, w.x, acc[rr][0]);
                acc[rr][1] = fmaf(a, w.y, acc[rr][1]);
                acc[rr][2] = fmaf(a, w.z, acc[rr][2]);
                acc[rr][3] = fmaf(a, w.w, acc[rr][3]);
            }
        }
    }
    #pragma unroll
    for (int rr = 0; rr < 8; ++rr) {
        const int r = r0b + rq * 8 + rr;
        if (r < NN)
            *(float4*)(C + (size_t)r * 256 + ch * 128 + cg * 4) =
                make_float4(acc[rr][0], acc[rr][1], acc[rr][2], acc[rr][3]);
    }
}

// ============================ Fused edge kernel ============================
// wave per node; lane L owns channels 4L..4L+3; We in 32 regs; 2-slot ping-pong prefetch;
// no-max softmax (logits are O(1) here: exp never overflows); DPP row reduce (no LDS pipe).
template <bool PERM>
__global__ __launch_bounds__(256, 4) void k_agg(const float* __restrict__ xl, float* __restrict__ xragg,
                                                const float* __restrict__ att, const float* __restrict__ gatb,
                                                const int* __restrict__ rowptr, const int* __restrict__ eid,
                                                const int* __restrict__ srcv, const float* __restrict__ eattr,
                                                const int* __restrict__ src_perm, const float4* __restrict__ ea_perm,
                                                const float* __restrict__ We) {
    const int lane = threadIdx.x & 63;
    const float4 we0 = ((const float4*)(We + 0 * 256))[lane];
    const float4 we1 = ((const float4*)(We + 1 * 256))[lane];
    const float4 we2 = ((const float4*)(We + 2 * 256))[lane];
    const float4 we3 = ((const float4*)(We + 3 * 256))[lane];
    const float4 we4 = ((const float4*)(We + 4 * 256))[lane];
    const float4 we5 = ((const float4*)(We + 5 * 256))[lane];
    const float4 we6 = ((const float4*)(We + 6 * 256))[lane];
    const float4 we7 = ((const float4*)(We + 7 * 256))[lane];
    const float4 attf = ((const float4*)att)[lane];
    const float4 gbf = ((const float4*)gatb)[lane];
    const int nw = gridDim.x * (blockDim.x >> 6);
    int wid = blockIdx.x * (blockDim.x >> 6) + (threadIdx.x >> 6);

#define LOADE(X, idx)                                                          \
    {                                                                          \
        int s_;                                                                \
        const float4* eap_;                                                    \
        if (PERM) {                                                            \
            s_ = src_perm[idx];                                                \
            eap_ = ea_perm + (size_t)(idx) * 2;                                \
        } else {                                                               \
            const int e_ = eid[idx];                                           \
            s_ = srcv[e_];                                                     \
            eap_ = (const float4*)(eattr + (size_t)e_ * 8);                    \
        }                                                                      \
        X##x = ((const float4*)(xl + (size_t)s_ * 256))[lane];                 \
        X##a = eap_[0];                                                        \
        X##b = eap_[1];                                                        \
    }

#define PROC(X)                                                                \
    {                                                                          \
        float v0 = fmaf(X##a.x, we0.x, xr.x), v1 = fmaf(X##a.x, we0.y, xr.y);  \
        float v2 = fmaf(X##a.x, we0.z, xr.z), v3 = fmaf(X##a.x, we0.w, xr.w);  \
        v0 = fmaf(X##a.y, we1.x, v0); v1 = fmaf(X##a.y, we1.y, v1);            \
        v2 = fmaf(X##a.y, we1.z, v2); v3 = fmaf(X##a.y, we1.w, v3);            \
        v0 = fmaf(X##a.z, we2.x, v0); v1 = fmaf(X##a.z, we2.y, v1);            \
        v2 = fmaf(X##a.z, we2.z, v2); v3 = fmaf(X##a.z, we2.w, v3);            \
        v0 = fmaf(X##a.w, we3.x, v0); v1 = fmaf(X##a.w, we3.y, v1);            \
        v2 = fmaf(X##a.w, we3.z, v2); v3 = fmaf(X##a.w, we3.w, v3);            \
        v0 = fmaf(X##b.x, we4.x, v0); v1 = fmaf(X##b.x, we4.y, v1);            \
        v2 = fmaf(X##b.x, we4.z, v2); v3 = fmaf(X##b.x, we4.w, v3);            \
        v0 = fmaf(X##b.y, we5.x, v0); v1 = fmaf(X##b.y, we5.y, v1);            \
        v2 = fmaf(X##b.y, we5.z, v2); v3 = fmaf(X##b.y, we5.w, v3);            \
        v0 = fmaf(X##b.z, we6.x, v0); v1 = fmaf(X##b.z, we6.y, v1);            \
        v2 = fmaf(X##b.z, we6.z, v2); v3 = fmaf(X##b.z, we6.w, v3);            \
        v0 = fmaf(X##b.w, we7.x, v0); v1 = fmaf(X##b.w, we7.y, v1);            \
        v2 = fmaf(X##b.w, we7.z, v2); v3 = fmaf(X##b.w, we7.w, v3);            \
        v0 += X##x.x; v1 += X##x.y; v2 += X##x.z; v3 += X##x.w;                \
        v0 = fmaxf(v0, 0.2f * v0); v1 = fmaxf(v1, 0.2f * v1);                  \
        v2 = fmaxf(v2, 0.2f * v2); v3 = fmaxf(v3, 0.2f * v3);                  \
        float part = v0 * attf.x;                                              \
        part = fmaf(v1, attf.y, part);                                         \
        part = fmaf(v2, attf.z, part);                                         \
        part = fmaf(v3, attf.w, part);                                         \
        part = dpp_add16(part);                                                \
        const float p = __expf(part);                                          \
        den += p;                                                              \
        c0 = fmaf(p, X##x.x, c0);                                              \
        c1 = fmaf(p, X##x.y, c1);                                              \
        c2 = fmaf(p, X##x.z, c2);                                              \
        c3 = fmaf(p, X##x.w, c3);                                              \
    }

    for (int n = wid; n < NN; n += nw) {
        const int e0 = rowptr[n], e1 = rowptr[n + 1];
        const float4 xr = ((const float4*)(xragg + (size_t)n * 256))[lane];
        float den = 0.f, c0 = 0.f, c1 = 0.f, c2 = 0.f, c3 = 0.f;
        float4 Ax, Aa, Ab, Bx, Ba, Bb;
        const int cnt = e1 - e0;
        if (cnt > 0) {
            LOADE(A, e0);
            if (cnt > 1) {
                LOADE(B, e0 + 1);
                int i = e0;
                for (; i + 3 < e1; i += 2) {
                    PROC(A);
                    LOADE(A, i + 2);
                    PROC(B);
                    LOADE(B, i + 3);
                }
                const int r = e1 - i; // 2 or 3
                PROC(A);
                if (r == 3) {
                    LOADE(A, i + 2);
                    PROC(B);
                    PROC(A);
                } else {
                    PROC(B);
                }
            } else {
                PROC(A);
            }
        }
        float4 o;
        if (cnt > 0) {
            const float inv = 1.0f / den;
            o.x = fmaf(c0, inv, gbf.x);
            o.y = fmaf(c1, inv, gbf.y);
            o.z = fmaf(c2, inv, gbf.z);
            o.w = fmaf(c3, inv, gbf.w);
        } else {
            o = gbf;
        }
        ((float4*)(xragg + (size_t)n * 256))[lane] = o;
    }
#undef LOADE
#undef PROC
}

// ============================ tr GEMM: [N,256]@[256,64] + bias, relu, BN stats ============================
__global__ __launch_bounds__(256) void k_tr(const float* __restrict__ A, const float* __restrict__ W,
                                            const float* __restrict__ bias, float* __restrict__ Hout,
                                            float* __restrict__ stats) {
    __shared__ float As[64 * 68]; // padded rows
    __shared__ float Ws[64 * 64]; // 16KB
    __shared__ float red[128];
    const int tid = threadIdx.x;
    const int cg = tid & 15;
    const int rq = tid >> 4;
    const int r0b = blockIdx.x * 64;

    float acc[4][4];
    {
        const float b0 = bias[cg * 4], b1 = bias[cg * 4 + 1], b2 = bias[cg * 4 + 2], b3 = bias[cg * 4 + 3];
        #pragma unroll
        for (int rr = 0; rr < 4; ++rr) { acc[rr][0] = b0; acc[rr][1] = b1; acc[rr][2] = b2; acc[rr][3] = b3; }
    }

    for (int kc = 0; kc < 4; ++kc) {
        if (kc) __syncthreads();
        for (int i = tid; i < 1024; i += 256)
            ((float4*)Ws)[i] = ((const float4*)(W + kc * 4096))[i];
        for (int i = tid; i < 1024; i += 256) {
            const int r = i >> 4, c4 = i & 15;
            const int rg = (r0b + r < NN) ? (r0b + r) : (NN - 1);
            *(float4*)(As + r * 68 + c4 * 4) = ((const float4*)A)[(size_t)rg * 64 + kc * 16 + c4];
        }
        __syncthreads();
        for (int kq = 0; kq < 16; ++kq) {
            float4 av[4];
            #pragma unroll
            for (int rr = 0; rr < 4; ++rr)
                av[rr] = *(const float4*)(As + (rq * 4 + rr) * 68 + kq * 4);
            #pragma unroll
            for (int kk = 0; kk < 4; ++kk) {
                const float4 w = *(const float4*)(Ws + ((kq * 4 + kk) << 6) + (cg << 2));
                #pragma unroll
                for (int rr = 0; rr < 4; ++rr) {
                    const float a = reinterpret_cast<const float*>(&av[rr])[kk];
                    acc[rr][0] = fmaf(a, w.x, acc[rr][0]);
                    acc[rr][1] = fmaf(a, w.y, acc[rr][1]);
                    acc[rr][2] = fmaf(a, w.z, acc[rr][2]);
                    acc[rr][3] = fmaf(a, w.w, acc[rr][3]);
                }
            }
        }
    }
    float lsum[4] = {0.f, 0.f, 0.f, 0.f}, lsq[4] = {0.f, 0.f, 0.f, 0.f};
    #pragma unroll
    for (int rr = 0; rr < 4; ++rr) {
        const int r = r0b + rq * 4 + rr;
        if (r < NN) {
            float v0 = fmaxf(acc[rr][0], 0.f), v1 = fmaxf(acc[rr][1], 0.f);
            float v2 = fmaxf(acc[rr][2], 0.f), v3 = fmaxf(acc[rr][3], 0.f);
            lsum[0] += v0; lsum[1] += v1; lsum[2] += v2; lsum[3] += v3;
            lsq[0] = fmaf(v0, v0, lsq[0]); lsq[1] = fmaf(v1, v1, lsq[1]);
            lsq[2] = fmaf(v2, v2, lsq[2]); lsq[3] = fmaf(v3, v3, lsq[3]);
            *(float4*)(Hout + (size_t)r * 64 + cg * 4) = make_float4(v0, v1, v2, v3);
        }
    }
    __syncthreads();
    if (tid < 128) red[tid] = 0.f;
    __syncthreads();
    #pragma unroll
    for (int j = 0; j < 4; ++j) {
        atomicAdd(&red[cg * 4 + j], lsum[j]);
        atomicAdd(&red[64 + cg * 4 + j], lsq[j]);
    }
    __syncthreads();
    if (tid < 64) {
        atomicAdd(&stats[tid], red[tid]);
        atomicAdd(&stats[64 + tid], red[64 + tid]);
    }
}

// ============================ fused gate + pool + BN fold + MLP head ============================
__global__ __launch_bounds__(256) void k_poolhead(const float* __restrict__ h, const float* __restrict__ gw,
                                                  const int* __restrict__ bidx, const float* __restrict__ stats,
                                                  const float* __restrict__ bg, const float* __restrict__ bb,
                                                  const float* __restrict__ fc, const float* __restrict__ nrot,
                                                  const float* __restrict__ W1, const float* __restrict__ b1,
                                                  const float* __restrict__ W2, const float* __restrict__ b2,
                                                  const float* __restrict__ W3, const float* __restrict__ b3,
                                                  const float* __restrict__ W4, const float* __restrict__ b4,
                                                  float* __restrict__ out) {
    __shared__ float gate_s[1024];
    __shared__ float red[4];
    __shared__ float pp[4][64];
    __shared__ float scb[64], shb[64];
    __shared__ float z[66], a1[256], a2[128], a3[64];
    const int b = blockIdx.x, tid = threadIdx.x, lane = tid & 63, w = tid >> 6;
    if (tid < 64) {
        const float mu = stats[tid] * (1.0f / (float)NN);
        const float var = stats[64 + tid] * (1.0f / (float)NN) - mu * mu;
        const float rstd = rsqrtf(var + 1e-5f);
        const float sc = bg[tid] * rstd;
        scb[tid] = sc;
        shb[tid] = fmaf(-mu, sc, bb[tid]);
    }
    int lo = 0, hi = NN;
    while (lo < hi) { int mid = (lo + hi) >> 1; if (bidx[mid] < b) lo = mid + 1; else hi = mid; }
    const int s0 = lo;
    lo = 0; hi = NN;
    while (lo < hi) { int mid = (lo + hi) >> 1; if (bidx[mid] < b + 1) lo = mid + 1; else hi = mid; }
    const int s1 = lo;
    const int seg = s1 - s0;
    __syncthreads();

    const float gwv = gw[lane] * scb[lane];
    for (int i = s0 + w; i < s1; i += 4) {
        float p = h[(size_t)i * 64 + lane] * gwv;
        #pragma unroll
        for (int off = 32; off; off >>= 1) p += __shfl_xor(p, off);
        if (lane == 0) gate_s[i - s0] = p;
    }
    __syncthreads();
    float v = NINF;
    for (int i = tid; i < seg; i += 256) v = fmaxf(v, gate_s[i]);
    #pragma unroll
    for (int off = 32; off; off >>= 1) v = fmaxf(v, __shfl_xor(v, off));
    if (lane == 0) red[w] = v;
    __syncthreads();
    const float mx = fmaxf(fmaxf(red[0], red[1]), fmaxf(red[2], red[3]));
    __syncthreads();
    float d = 0.f;
    for (int i = tid; i < seg; i += 256) {
        const float ex = __expf(gate_s[i] - mx);
        gate_s[i] = ex;
        d += ex;
    }
    #pragma unroll
    for (int off = 32; off; off >>= 1) d += __shfl_xor(d, off);
    if (lane == 0) red[w] = d;
    __syncthreads();
    const float den = red[0] + red[1] + red[2] + red[3];
    const int c = tid & 63, ro = tid >> 6;
    float acc = 0.f;
    for (int i = s0 + ro; i < s1; i += 4) acc = fmaf(gate_s[i - s0], h[(size_t)i * 64 + c], acc);
    pp[ro][c] = acc;
    __syncthreads();
    if (tid < 64) {
        const float raw = (pp[0][tid] + pp[1][tid] + pp[2][tid] + pp[3][tid]) / den;
        z[tid] = (seg > 0) ? fmaf(raw, scb[tid], shb[tid]) : shb[tid];
    }
    if (tid == 64) z[64] = fc[b];
    if (tid == 65) z[65] = nrot[b];
    __syncthreads();
    float s = b1[tid];
    for (int k = 0; k < 66; ++k) s = fmaf(z[k], W1[k * 256 + tid], s);
    a1[tid] = fmaxf(s, 0.f);
    __syncthreads();
    if (tid < 128) {
        float s2 = b2[tid];
        for (int k = 0; k < 256; ++k) s2 = fmaf(a1[k], W2[k * 128 + tid], s2);
        a2[tid] = fmaxf(s2, 0.f);
    }
    __syncthreads();
    if (tid < 64) {
        float s3 = b3[tid];
        for (int k = 0; k < 128; ++k) s3 = fmaf(a2[k], W3[k * 64 + tid], s3);
        a3[tid] = fmaxf(s3, 0.f);
    }
    __syncthreads();
    if (tid < 64) {
        float p = a3[tid] * W4[tid];
        #pragma unroll
        for (int off = 32; off; off >>= 1) p += __shfl_xor(p, off);
        if (tid == 0) out[b] = p + b4[0];
    }
}

// ============================ launch ============================
extern "C" void kernel_launch(void* const* d_in, const int* in_sizes, int n_in,
                              void* d_out, int out_size, void* d_ws, size_t ws_size,
                              hipStream_t stream) {
    const float* x     = (const float*)d_in[0];
    const int*   ei    = (const int*)d_in[1];
    const float* eattr = (const float*)d_in[2];
    const float* fcv   = (const float*)d_in[3];
    const float* nrot  = (const float*)d_in[4];
    const int*   bidx  = (const int*)d_in[5];
    const float* Wl    = (const float*)d_in[6];
    const float* Wr    = (const float*)d_in[7];
    const float* We    = (const float*)d_in[8];
    const float* att   = (const float*)d_in[9];
    const float* gatb  = (const float*)d_in[10];
    const float* trW   = (const float*)d_in[11];
    const float* trb   = (const float*)d_in[12];
    const float* bng   = (const float*)d_in[13];
    const float* bnb   = (const float*)d_in[14];
    const float* gateW = (const float*)d_in[15];
    const float* W1    = (const float*)d_in[17];
    const float* b1    = (const float*)d_in[18];
    const float* W2    = (const float*)d_in[19];
    const float* b2    = (const float*)d_in[20];
    const float* W3    = (const float*)d_in[21];
    const float* b3    = (const float*)d_in[22];
    const float* W4    = (const float*)d_in[23];
    const float* b4    = (const float*)d_in[24];
    float* out = (float*)d_out;

    const int* srcv = ei;
    const int* dstv = ei + NE;

    char* w = (char*)d_ws;
    float*  xl       = (float*)(w);                 // 51,200,000
    float*  xragg    = (float*)(w + 51200000);      // 51,200,000 (xr in, agg out)
    float*  hbuf     = (float*)(w + 102400000);     // 12,800,000
    int*    deg      = (int*)  (w + 102400000);     // overlaps hbuf (dead before first k_tr)
    int*    cnt      = (int*)  (w + 102600000);     // overlaps hbuf
    int*    eid      = (int*)  (w + 115200000);     // 1,600,000
    int*    rowptr   = (int*)  (w + 116800000);     // 200,004
    float*  stats    = (float*)(w + 117000064);     // 1,536 (3 * 128 * 4)
    int*    src_perm = (int*)  (w + 117042048);     // 1,600,000
    float4* ea_perm  = (float4*)(w + 118642048);    // 12,800,000 -> 131,442,048
    const bool use_perm = (ws_size >= (size_t)131442048);

    hipMemsetAsync(deg, 0, 400000, stream);         // deg + cnt
    hipMemsetAsync(stats, 0, 1536, stream);
    k_hist<<<(NE + 255) / 256, 256, 0, stream>>>(dstv, deg);
    k_scan<<<1, 1024, 0, stream>>>(deg, rowptr);
    k_scatter<<<(NE + 255) / 256, 256, 0, stream>>>(dstv, srcv, eattr, rowptr, cnt, eid,
                                                    src_perm, ea_perm, use_perm ? 1 : 0);

    const float* hin = x;
    for (int l = 0; l < 3; ++l) {
        const float* st = (l == 0) ? nullptr : (stats + (l - 1) * 128);
        const float* g  = (l == 0) ? nullptr : (bng + (l - 1) * 64);
        const float* bb = (l == 0) ? nullptr : (bnb + (l - 1) * 64);
        dim3 gg((NN + 63) / 64, 4);
        k_gemm64<<<gg, 256, 0, stream>>>(hin, Wl + l * 16384, Wr + l * 16384, xl, xragg, st, g, bb);
        if (use_perm)
            k_agg<true><<<2048, 256, 0, stream>>>(xl, xragg, att + l * 256, gatb + l * 256, rowptr,
                                                  eid, srcv, eattr, src_perm, ea_perm, We + l * 2048);
        else
            k_agg<false><<<2048, 256, 0, stream>>>(xl, xragg, att + l * 256, gatb + l * 256, rowptr,
                                                   eid, srcv, eattr, src_perm, ea_perm, We + l * 2048);
        k_tr<<<(NN + 63) / 64, 256, 0, stream>>>(xragg, trW + l * 16384, trb + l * 64, hbuf, stats + l * 128);
        hin = hbuf;
    }
    k_poolhead<<<NB, 256, 0, stream>>>(hbuf, gateW, bidx, stats + 2 * 128, bng + 128, bnb + 128,
                                       fcv, nrot, W1, b1, W2, b2, W3, b3, W4, b4, out);
}

// Round 6
// 754.716 us; speedup vs baseline: 1.0498x; 1.0063x over previous
//
#include <hip/hip_runtime.h>

#define NN 50000
#define NE 400000
#define NB 128
#define NINF (-__builtin_inff())

__device__ __forceinline__ float dpp_add16(float x) {
    int v = __float_as_int(x);
    x += __int_as_float(__builtin_amdgcn_update_dpp(0, v, 0xB1, 0xF, 0xF, true));  // quad_perm(1,0,3,2)
    v = __float_as_int(x);
    x += __int_as_float(__builtin_amdgcn_update_dpp(0, v, 0x4E, 0xF, 0xF, true));  // quad_perm(2,3,0,1)
    v = __float_as_int(x);
    x += __int_as_float(__builtin_amdgcn_update_dpp(0, v, 0x141, 0xF, 0xF, true)); // row_half_mirror
    v = __float_as_int(x);
    x += __int_as_float(__builtin_amdgcn_update_dpp(0, v, 0x140, 0xF, 0xF, true)); // row_mirror
    return x;
}

// ============================ CSR build ============================
__global__ __launch_bounds__(256) void k_hist(const int* __restrict__ dstv, int* __restrict__ deg) {
    int e = blockIdx.x * 256 + threadIdx.x;
    if (e < NE) atomicAdd(&deg[dstv[e]], 1);
}

// 3-phase parallel scan over deg[NN] -> rowptr (exclusive, rowptr[0]=0, rowptr[i+1]=incl[i])
__global__ __launch_bounds__(256) void k_scan1(const int* __restrict__ deg, int* __restrict__ bsum) {
    __shared__ int ws[4];
    const int tid = threadIdx.x, lane = tid & 63, w = tid >> 6;
    const int i = blockIdx.x * 256 + tid;
    int v = (i < NN) ? deg[i] : 0;
    #pragma unroll
    for (int off = 32; off; off >>= 1) v += __shfl_xor(v, off);
    if (lane == 0) ws[w] = v;
    __syncthreads();
    if (tid == 0) bsum[blockIdx.x] = ws[0] + ws[1] + ws[2] + ws[3];
}

__global__ __launch_bounds__(256) void k_scan2(const int* __restrict__ bsum, int* __restrict__ boff, int nblk) {
    __shared__ int ws[4];
    const int tid = threadIdx.x, lane = tid & 63, w = tid >> 6;
    int v = (tid < nblk) ? bsum[tid] : 0;
    int incl = v;
    #pragma unroll
    for (int off = 1; off < 64; off <<= 1) {
        int t = __shfl_up(incl, off);
        if (lane >= off) incl += t;
    }
    if (lane == 63) ws[w] = incl;
    __syncthreads();
    int add = 0;
    for (int k = 0; k < w; ++k) add += ws[k];
    if (tid < nblk) boff[tid] = add + incl - v;
}

__global__ __launch_bounds__(256) void k_scan3(const int* __restrict__ deg, const int* __restrict__ boff,
                                               int* __restrict__ rowptr) {
    __shared__ int ws[4];
    const int tid = threadIdx.x, lane = tid & 63, w = tid >> 6;
    const int i = blockIdx.x * 256 + tid;
    int v = (i < NN) ? deg[i] : 0;
    int incl = v;
    #pragma unroll
    for (int off = 1; off < 64; off <<= 1) {
        int t = __shfl_up(incl, off);
        if (lane >= off) incl += t;
    }
    if (lane == 63) ws[w] = incl;
    __syncthreads();
    int add = boff[blockIdx.x];
    for (int k = 0; k < w; ++k) add += ws[k];
    if (i < NN) rowptr[i + 1] = add + incl;
    if (i == 0) rowptr[0] = 0;
}

// scatter + permute fused: writes CSR-ordered src / edge_attr directly
__global__ __launch_bounds__(256) void k_scatter(const int* __restrict__ dstv, const int* __restrict__ srcv,
                                                 const float* __restrict__ eattr, const int* __restrict__ rowptr,
                                                 int* __restrict__ cnt, int* __restrict__ eid,
                                                 int* __restrict__ src_perm, float4* __restrict__ ea_perm,
                                                 int use_perm) {
    int e = blockIdx.x * 256 + threadIdx.x;
    if (e < NE) {
        int d = dstv[e];
        int pos = rowptr[d] + atomicAdd(&cnt[d], 1);
        eid[pos] = e;
        if (use_perm) {
            src_perm[pos] = srcv[e];
            ea_perm[(size_t)pos * 2] = ((const float4*)eattr)[e * 2];
            ea_perm[(size_t)pos * 2 + 1] = ((const float4*)eattr)[e * 2 + 1];
        }
    }
}

// ============================ GEMM: [N,64] @ [64,256] -> xl / xr ============================
// 128 rows x 128 cols per block; 8x8 microtile (cols cg*4..+3 and 64+cg*4..+3).
// A staged TRANSPOSED in LDS (At[k][r], pad 132): broadcast A reads, 2.0 FLOP/LDS-byte.
// blockIdx.y: bit0 = col half, bit1 = mat. BN of prev layer folded in-kernel.
__global__ __launch_bounds__(256) void k_gemm64(const float* __restrict__ A, const float* __restrict__ Wl,
                                                const float* __restrict__ Wr, float* __restrict__ Cl,
                                                float* __restrict__ Cr, const float* __restrict__ stats,
                                                const float* __restrict__ bg, const float* __restrict__ bb) {
    __shared__ float At[64 * 132];  // 33,792 B
    __shared__ float Ws[64 * 128];  // 32,768 B
    __shared__ float sc_s[64], sh_s[64], shW_s[128];
    const int tid = threadIdx.x;
    const int mat = blockIdx.y >> 1, ch = blockIdx.y & 1;
    const float* W = mat ? Wr : Wl;
    float* C = mat ? Cr : Cl;
    const int r0b = blockIdx.x * 128;

    if (stats) {
        if (tid < 64) {
            const float mu = stats[tid] * (1.0f / (float)NN);
            const float var = stats[64 + tid] * (1.0f / (float)NN) - mu * mu;
            const float rstd = rsqrtf(var + 1e-5f);
            const float sc = bg[tid] * rstd;
            sc_s[tid] = sc;
            sh_s[tid] = fmaf(-mu, sc, bb[tid]);
        }
        __syncthreads();
    }
    // W stage: Ws[k][c] for this 128-col half (scaled by sc if BN)
    for (int i = tid; i < 2048; i += 256) {
        const int k = i >> 5, c4 = i & 31;
        float4 v = ((const float4*)W)[k * 64 + ch * 32 + c4];
        if (stats) {
            const float s = sc_s[k];
            v.x *= s; v.y *= s; v.z *= s; v.w *= s;
        }
        ((float4*)Ws)[i] = v;
    }
    // A stage transposed: At[k][r]
    for (int i = tid; i < 2048; i += 256) {
        const int r = i >> 4, kq = i & 15;
        const int rg = (r0b + r < NN) ? (r0b + r) : (NN - 1);
        const float4 v = ((const float4*)A)[rg * 16 + kq];
        At[(kq * 4 + 0) * 132 + r] = v.x;
        At[(kq * 4 + 1) * 132 + r] = v.y;
        At[(kq * 4 + 2) * 132 + r] = v.z;
        At[(kq * 4 + 3) * 132 + r] = v.w;
    }
    if (stats && tid < 128) {
        const float* wc = W + ch * 128 + tid;
        float s = 0.f;
        for (int k = 0; k < 64; ++k) s = fmaf(sh_s[k], wc[k * 256], s);
        shW_s[tid] = s;
    }
    __syncthreads();

    const int cg = tid & 15; // cols cg*4..+3 and 64+cg*4..+3
    const int rg = tid >> 4; // rows rg*8..+7
    float acc[8][8];
    if (stats) {
        #pragma unroll
        for (int rr = 0; rr < 8; ++rr)
            #pragma unroll
            for (int j = 0; j < 8; ++j)
                acc[rr][j] = (j < 4) ? shW_s[cg * 4 + j] : shW_s[64 + cg * 4 + (j - 4)];
    } else {
        #pragma unroll
        for (int rr = 0; rr < 8; ++rr)
            #pragma unroll
            for (int j = 0; j < 8; ++j) acc[rr][j] = 0.f;
    }

    #pragma unroll 4
    for (int k = 0; k < 64; ++k) {
        const float4 a0 = *(const float4*)(At + k * 132 + rg * 8);
        const float4 a1 = *(const float4*)(At + k * 132 + rg * 8 + 4);
        const float4 w0 = *(const float4*)(Ws + k * 128 + cg * 4);
        const float4 w1 = *(const float4*)(Ws + k * 128 + 64 + cg * 4);
        const float ar[8] = {a0.x, a0.y, a0.z, a0.w, a1.x, a1.y, a1.z, a1.w};
        #pragma unroll
        for (int rr = 0; rr < 8; ++rr) {
            acc[rr][0] = fmaf(ar[rr], w0.x, acc[rr][0]);
            acc[rr][1] = fmaf(ar[rr], w0.y, acc[rr][1]);
            acc[rr][2] = fmaf(ar[rr], w0.z, acc[rr][2]);
            acc[rr][3] = fmaf(ar[rr], w0.w, acc[rr][3]);
            acc[rr][4] = fmaf(ar[rr], w1.x, acc[rr][4]);
            acc[rr][5] = fmaf(ar[rr], w1.y, acc[rr][5]);
            acc[rr][6] = fmaf(ar[rr], w1.z, acc[rr][6]);
            acc[rr][7] = fmaf(ar[rr], w1.w, acc[rr][7]);
        }
    }
    #pragma unroll
    for (int rr = 0; rr < 8; ++rr) {
        const int r = r0b + rg * 8 + rr;
        if (r < NN) {
            float* cp = C + (size_t)r * 256 + ch * 128 + cg * 4;
            *(float4*)cp = make_float4(acc[rr][0], acc[rr][1], acc[rr][2], acc[rr][3]);
            *(float4*)(cp + 64) = make_float4(acc[rr][4], acc[rr][5], acc[rr][6], acc[rr][7]);
        }
    }
}

// ============================ Fused edge kernel ============================
template <bool PERM>
__global__ __launch_bounds__(256, 4) void k_agg(const float* __restrict__ xl, float* __restrict__ xragg,
                                                const float* __restrict__ att, const float* __restrict__ gatb,
                                                const int* __restrict__ rowptr, const int* __restrict__ eid,
                                                const int* __restrict__ srcv, const float* __restrict__ eattr,
                                                const int* __restrict__ src_perm, const float4* __restrict__ ea_perm,
                                                const float* __restrict__ We) {
    const int lane = threadIdx.x & 63;
    const float4 we0 = ((const float4*)(We + 0 * 256))[lane];
    const float4 we1 = ((const float4*)(We + 1 * 256))[lane];
    const float4 we2 = ((const float4*)(We + 2 * 256))[lane];
    const float4 we3 = ((const float4*)(We + 3 * 256))[lane];
    const float4 we4 = ((const float4*)(We + 4 * 256))[lane];
    const float4 we5 = ((const float4*)(We + 5 * 256))[lane];
    const float4 we6 = ((const float4*)(We + 6 * 256))[lane];
    const float4 we7 = ((const float4*)(We + 7 * 256))[lane];
    const float4 attf = ((const float4*)att)[lane];
    const float4 gbf = ((const float4*)gatb)[lane];
    const int nw = gridDim.x * (blockDim.x >> 6);
    int wid = blockIdx.x * (blockDim.x >> 6) + (threadIdx.x >> 6);

#define LOADE(X, idx)                                                          \
    {                                                                          \
        int s_;                                                                \
        const float4* eap_;                                                    \
        if (PERM) {                                                            \
            s_ = src_perm[idx];                                                \
            eap_ = ea_perm + (size_t)(idx) * 2;                                \
        } else {                                                               \
            const int e_ = eid[idx];                                           \
            s_ = srcv[e_];                                                     \
            eap_ = (const float4*)(eattr + (size_t)e_ * 8);                    \
        }                                                                      \
        X##x = ((const float4*)(xl + (size_t)s_ * 256))[lane];                 \
        X##a = eap_[0];                                                        \
        X##b = eap_[1];                                                        \
    }

#define PROC(X)                                                                \
    {                                                                          \
        float v0 = fmaf(X##a.x, we0.x, xr.x), v1 = fmaf(X##a.x, we0.y, xr.y);  \
        float v2 = fmaf(X##a.x, we0.z, xr.z), v3 = fmaf(X##a.x, we0.w, xr.w);  \
        v0 = fmaf(X##a.y, we1.x, v0); v1 = fmaf(X##a.y, we1.y, v1);            \
        v2 = fmaf(X##a.y, we1.z, v2); v3 = fmaf(X##a.y, we1.w, v3);            \
        v0 = fmaf(X##a.z, we2.x, v0); v1 = fmaf(X##a.z, we2.y, v1);            \
        v2 = fmaf(X##a.z, we2.z, v2); v3 = fmaf(X##a.z, we2.w, v3);            \
        v0 = fmaf(X##a.w, we3.x, v0); v1 = fmaf(X##a.w, we3.y, v1);            \
        v2 = fmaf(X##a.w, we3.z, v2); v3 = fmaf(X##a.w, we3.w, v3);            \
        v0 = fmaf(X##b.x, we4.x, v0); v1 = fmaf(X##b.x, we4.y, v1);            \
        v2 = fmaf(X##b.x, we4.z, v2); v3 = fmaf(X##b.x, we4.w, v3);            \
        v0 = fmaf(X##b.y, we5.x, v0); v1 = fmaf(X##b.y, we5.y, v1);            \
        v2 = fmaf(X##b.y, we5.z, v2); v3 = fmaf(X##b.y, we5.w, v3);            \
        v0 = fmaf(X##b.z, we6.x, v0); v1 = fmaf(X##b.z, we6.y, v1);            \
        v2 = fmaf(X##b.z, we6.z, v2); v3 = fmaf(X##b.z, we6.w, v3);            \
        v0 = fmaf(X##b.w, we7.x, v0); v1 = fmaf(X##b.w, we7.y, v1);            \
        v2 = fmaf(X##b.w, we7.z, v2); v3 = fmaf(X##b.w, we7.w, v3);            \
        v0 += X##x.x; v1 += X##x.y; v2 += X##x.z; v3 += X##x.w;                \
        v0 = fmaxf(v0, 0.2f * v0); v1 = fmaxf(v1, 0.2f * v1);                  \
        v2 = fmaxf(v2, 0.2f * v2); v3 = fmaxf(v3, 0.2f * v3);                  \
        float part = v0 * attf.x;                                              \
        part = fmaf(v1, attf.y, part);                                         \
        part = fmaf(v2, attf.z, part);                                         \
        part = fmaf(v3, attf.w, part);                                         \
        part = dpp_add16(part);                                                \
        const float p = __expf(part);                                          \
        den += p;                                                              \
        c0 = fmaf(p, X##x.x, c0);                                              \
        c1 = fmaf(p, X##x.y, c1);                                              \
        c2 = fmaf(p, X##x.z, c2);                                              \
        c3 = fmaf(p, X##x.w, c3);                                              \
    }

    for (int n = wid; n < NN; n += nw) {
        const int e0 = rowptr[n], e1 = rowptr[n + 1];
        const float4 xr = ((const float4*)(xragg + (size_t)n * 256))[lane];
        float den = 0.f, c0 = 0.f, c1 = 0.f, c2 = 0.f, c3 = 0.f;
        float4 Ax, Aa, Ab, Bx, Ba, Bb;
        const int cnt = e1 - e0;
        if (cnt > 0) {
            LOADE(A, e0);
            if (cnt > 1) {
                LOADE(B, e0 + 1);
                int i = e0;
                for (; i + 3 < e1; i += 2) {
                    PROC(A);
                    LOADE(A, i + 2);
                    PROC(B);
                    LOADE(B, i + 3);
                }
                const int r = e1 - i; // 2 or 3
                PROC(A);
                if (r == 3) {
                    LOADE(A, i + 2);
                    PROC(B);
                    PROC(A);
                } else {
                    PROC(B);
                }
            } else {
                PROC(A);
            }
        }
        float4 o;
        if (cnt > 0) {
            const float inv = 1.0f / den;
            o.x = fmaf(c0, inv, gbf.x);
            o.y = fmaf(c1, inv, gbf.y);
            o.z = fmaf(c2, inv, gbf.z);
            o.w = fmaf(c3, inv, gbf.w);
        } else {
            o = gbf;
        }
        ((float4*)(xragg + (size_t)n * 256))[lane] = o;
    }
#undef LOADE
#undef PROC
}

// ============================ tr GEMM: [N,256]@[256,64] + bias, relu, BN stats ============================
// 128 rows x 64 cols per block, 128 threads, 8x8 microtile; K chunked x32 with transposed-A LDS.
__global__ __launch_bounds__(128) void k_tr(const float* __restrict__ A, const float* __restrict__ W,
                                            const float* __restrict__ bias, float* __restrict__ Hout,
                                            float* __restrict__ stats) {
    __shared__ float At[32 * 132]; // 16,896 B (transposed chunk, pad 132)
    __shared__ float Ws[32 * 64];  // 8,192 B
    __shared__ float red[128];
    const int tid = threadIdx.x;
    const int cg = tid & 7;  // cols cg*4..+3 and 32+cg*4..+3
    const int rg = tid >> 3; // rows rg*8..+7 (0..15)
    const int r0b = blockIdx.x * 128;

    float acc[8][8];
    #pragma unroll
    for (int rr = 0; rr < 8; ++rr)
        #pragma unroll
        for (int j = 0; j < 8; ++j)
            acc[rr][j] = bias[(j < 4) ? (cg * 4 + j) : (32 + cg * 4 + (j - 4))];

    for (int kc = 0; kc < 8; ++kc) {
        if (kc) __syncthreads();
        // W chunk: rows kc*32..+31
        for (int i = tid; i < 512; i += 128)
            ((float4*)Ws)[i] = ((const float4*)(W + kc * 2048))[i];
        // A chunk transposed: At[k][r], k in [0,32), r in [0,128)
        for (int i = tid; i < 1024; i += 128) {
            const int r = i >> 3, c4 = i & 7;
            const int rgl = (r0b + r < NN) ? (r0b + r) : (NN - 1);
            const float4 v = ((const float4*)A)[(size_t)rgl * 64 + kc * 8 + c4];
            At[(c4 * 4 + 0) * 132 + r] = v.x;
            At[(c4 * 4 + 1) * 132 + r] = v.y;
            At[(c4 * 4 + 2) * 132 + r] = v.z;
            At[(c4 * 4 + 3) * 132 + r] = v.w;
        }
        __syncthreads();
        #pragma unroll 4
        for (int k = 0; k < 32; ++k) {
            const float4 a0 = *(const float4*)(At + k * 132 + rg * 8);
            const float4 a1 = *(const float4*)(At + k * 132 + rg * 8 + 4);
            const float4 w0 = *(const float4*)(Ws + k * 64 + cg * 4);
            const float4 w1 = *(const float4*)(Ws + k * 64 + 32 + cg * 4);
            const float ar[8] = {a0.x, a0.y, a0.z, a0.w, a1.x, a1.y, a1.z, a1.w};
            #pragma unroll
            for (int rr = 0; rr < 8; ++rr) {
                acc[rr][0] = fmaf(ar[rr], w0.x, acc[rr][0]);
                acc[rr][1] = fmaf(ar[rr], w0.y, acc[rr][1]);
                acc[rr][2] = fmaf(ar[rr], w0.z, acc[rr][2]);
                acc[rr][3] = fmaf(ar[rr], w0.w, acc[rr][3]);
                acc[rr][4] = fmaf(ar[rr], w1.x, acc[rr][4]);
                acc[rr][5] = fmaf(ar[rr], w1.y, acc[rr][5]);
                acc[rr][6] = fmaf(ar[rr], w1.z, acc[rr][6]);
                acc[rr][7] = fmaf(ar[rr], w1.w, acc[rr][7]);
            }
        }
    }
    float lsum[8], lsq[8];
    #pragma unroll
    for (int j = 0; j < 8; ++j) { lsum[j] = 0.f; lsq[j] = 0.f; }
    #pragma unroll
    for (int rr = 0; rr < 8; ++rr) {
        const int r = r0b + rg * 8 + rr;
        if (r < NN) {
            float v[8];
            #pragma unroll
            for (int j = 0; j < 8; ++j) {
                v[j] = fmaxf(acc[rr][j], 0.f);
                lsum[j] += v[j];
                lsq[j] = fmaf(v[j], v[j], lsq[j]);
            }
            float* hp = Hout + (size_t)r * 64;
            *(float4*)(hp + cg * 4) = make_float4(v[0], v[1], v[2], v[3]);
            *(float4*)(hp + 32 + cg * 4) = make_float4(v[4], v[5], v[6], v[7]);
        }
    }
    __syncthreads();
    red[tid] = 0.f;
    __syncthreads();
    #pragma unroll
    for (int j = 0; j < 8; ++j) {
        const int c = (j < 4) ? (cg * 4 + j) : (32 + cg * 4 + (j - 4));
        atomicAdd(&red[c], lsum[j]);
        atomicAdd(&red[64 + c], lsq[j]);
    }
    __syncthreads();
    if (tid < 64) {
        atomicAdd(&stats[tid], red[tid]);
        atomicAdd(&stats[64 + tid], red[64 + tid]);
    }
}

// ============================ fused gate + pool + BN fold + MLP head ============================
__global__ __launch_bounds__(256) void k_poolhead(const float* __restrict__ h, const float* __restrict__ gw,
                                                  const int* __restrict__ bidx, const float* __restrict__ stats,
                                                  const float* __restrict__ bg, const float* __restrict__ bb,
                                                  const float* __restrict__ fc, const float* __restrict__ nrot,
                                                  const float* __restrict__ W1, const float* __restrict__ b1,
                                                  const float* __restrict__ W2, const float* __restrict__ b2,
                                                  const float* __restrict__ W3, const float* __restrict__ b3,
                                                  const float* __restrict__ W4, const float* __restrict__ b4,
                                                  float* __restrict__ out) {
    __shared__ float gate_s[1024];
    __shared__ float red[4];
    __shared__ float pp[4][64];
    __shared__ float scb[64], shb[64];
    __shared__ float z[66], a1[256], a2[128], a3[64];
    const int b = blockIdx.x, tid = threadIdx.x, lane = tid & 63, w = tid >> 6;
    if (tid < 64) {
        const float mu = stats[tid] * (1.0f / (float)NN);
        const float var = stats[64 + tid] * (1.0f / (float)NN) - mu * mu;
        const float rstd = rsqrtf(var + 1e-5f);
        const float sc = bg[tid] * rstd;
        scb[tid] = sc;
        shb[tid] = fmaf(-mu, sc, bb[tid]);
    }
    int lo = 0, hi = NN;
    while (lo < hi) { int mid = (lo + hi) >> 1; if (bidx[mid] < b) lo = mid + 1; else hi = mid; }
    const int s0 = lo;
    lo = 0; hi = NN;
    while (lo < hi) { int mid = (lo + hi) >> 1; if (bidx[mid] < b + 1) lo = mid + 1; else hi = mid; }
    const int s1 = lo;
    const int seg = s1 - s0;
    __syncthreads();

    const float gwv = gw[lane] * scb[lane];
    for (int i = s0 + w; i < s1; i += 4) {
        float p = h[(size_t)i * 64 + lane] * gwv;
        #pragma unroll
        for (int off = 32; off; off >>= 1) p += __shfl_xor(p, off);
        if (lane == 0) gate_s[i - s0] = p;
    }
    __syncthreads();
    float v = NINF;
    for (int i = tid; i < seg; i += 256) v = fmaxf(v, gate_s[i]);
    #pragma unroll
    for (int off = 32; off; off >>= 1) v = fmaxf(v, __shfl_xor(v, off));
    if (lane == 0) red[w] = v;
    __syncthreads();
    const float mx = fmaxf(fmaxf(red[0], red[1]), fmaxf(red[2], red[3]));
    __syncthreads();
    float d = 0.f;
    for (int i = tid; i < seg; i += 256) {
        const float ex = __expf(gate_s[i] - mx);
        gate_s[i] = ex;
        d += ex;
    }
    #pragma unroll
    for (int off = 32; off; off >>= 1) d += __shfl_xor(d, off);
    if (lane == 0) red[w] = d;
    __syncthreads();
    const float den = red[0] + red[1] + red[2] + red[3];
    const int c = tid & 63, ro = tid >> 6;
    float acc = 0.f;
    for (int i = s0 + ro; i < s1; i += 4) acc = fmaf(gate_s[i - s0], h[(size_t)i * 64 + c], acc);
    pp[ro][c] = acc;
    __syncthreads();
    if (tid < 64) {
        const float raw = (pp[0][tid] + pp[1][tid] + pp[2][tid] + pp[3][tid]) / den;
        z[tid] = (seg > 0) ? fmaf(raw, scb[tid], shb[tid]) : shb[tid];
    }
    if (tid == 64) z[64] = fc[b];
    if (tid == 65) z[65] = nrot[b];
    __syncthreads();
    float s = b1[tid];
    for (int k = 0; k < 66; ++k) s = fmaf(z[k], W1[k * 256 + tid], s);
    a1[tid] = fmaxf(s, 0.f);
    __syncthreads();
    if (tid < 128) {
        float s2 = b2[tid];
        for (int k = 0; k < 256; ++k) s2 = fmaf(a1[k], W2[k * 128 + tid], s2);
        a2[tid] = fmaxf(s2, 0.f);
    }
    __syncthreads();
    if (tid < 64) {
        float s3 = b3[tid];
        for (int k = 0; k < 128; ++k) s3 = fmaf(a2[k], W3[k * 64 + tid], s3);
        a3[tid] = fmaxf(s3, 0.f);
    }
    __syncthreads();
    if (tid < 64) {
        float p = a3[tid] * W4[tid];
        #pragma unroll
        for (int off = 32; off; off >>= 1) p += __shfl_xor(p, off);
        if (tid == 0) out[b] = p + b4[0];
    }
}

// ============================ launch ============================
extern "C" void kernel_launch(void* const* d_in, const int* in_sizes, int n_in,
                              void* d_out, int out_size, void* d_ws, size_t ws_size,
                              hipStream_t stream) {
    const float* x     = (const float*)d_in[0];
    const int*   ei    = (const int*)d_in[1];
    const float* eattr = (const float*)d_in[2];
    const float* fcv   = (const float*)d_in[3];
    const float* nrot  = (const float*)d_in[4];
    const int*   bidx  = (const int*)d_in[5];
    const float* Wl    = (const float*)d_in[6];
    const float* Wr    = (const float*)d_in[7];
    const float* We    = (const float*)d_in[8];
    const float* att   = (const float*)d_in[9];
    const float* gatb  = (const float*)d_in[10];
    const float* trW   = (const float*)d_in[11];
    const float* trb   = (const float*)d_in[12];
    const float* bng   = (const float*)d_in[13];
    const float* bnb   = (const float*)d_in[14];
    const float* gateW = (const float*)d_in[15];
    const float* W1    = (const float*)d_in[17];
    const float* b1    = (const float*)d_in[18];
    const float* W2    = (const float*)d_in[19];
    const float* b2    = (const float*)d_in[20];
    const float* W3    = (const float*)d_in[21];
    const float* b3    = (const float*)d_in[22];
    const float* W4    = (const float*)d_in[23];
    const float* b4    = (const float*)d_in[24];
    float* out = (float*)d_out;

    const int* srcv = ei;
    const int* dstv = ei + NE;

    char* w = (char*)d_ws;
    float*  xl       = (float*)(w);                 // 51,200,000
    float*  xragg    = (float*)(w + 51200000);      // 51,200,000 (xr in, agg out)
    float*  hbuf     = (float*)(w + 102400000);     // 12,800,000
    int*    deg      = (int*)  (w + 102400000);     // overlaps hbuf (dead before first k_tr)
    int*    cnt      = (int*)  (w + 102600000);     // overlaps hbuf
    int*    eid      = (int*)  (w + 115200000);     // 1,600,000
    int*    rowptr   = (int*)  (w + 116800000);     // 200,004
    float*  stats    = (float*)(w + 117000064);     // 1,536 (3 * 128 * 4)
    int*    bsum     = (int*)  (w + 117004096);     // 784
    int*    boff     = (int*)  (w + 117006144);     // 784
    int*    src_perm = (int*)  (w + 117042048);     // 1,600,000
    float4* ea_perm  = (float4*)(w + 118642048);    // 12,800,000 -> 131,442,048
    const bool use_perm = (ws_size >= (size_t)131442048);
    const int NBLK = (NN + 255) / 256; // 196

    hipMemsetAsync(deg, 0, 400000, stream);         // deg + cnt
    hipMemsetAsync(stats, 0, 1536, stream);
    k_hist<<<(NE + 255) / 256, 256, 0, stream>>>(dstv, deg);
    k_scan1<<<NBLK, 256, 0, stream>>>(deg, bsum);
    k_scan2<<<1, 256, 0, stream>>>(bsum, boff, NBLK);
    k_scan3<<<NBLK, 256, 0, stream>>>(deg, boff, rowptr);
    k_scatter<<<(NE + 255) / 256, 256, 0, stream>>>(dstv, srcv, eattr, rowptr, cnt, eid,
                                                    src_perm, ea_perm, use_perm ? 1 : 0);

    const float* hin = x;
    for (int l = 0; l < 3; ++l) {
        const float* st = (l == 0) ? nullptr : (stats + (l - 1) * 128);
        const float* g  = (l == 0) ? nullptr : (bng + (l - 1) * 64);
        const float* bb = (l == 0) ? nullptr : (bnb + (l - 1) * 64);
        dim3 gg((NN + 127) / 128, 4);
        k_gemm64<<<gg, 256, 0, stream>>>(hin, Wl + l * 16384, Wr + l * 16384, xl, xragg, st, g, bb);
        if (use_perm)
            k_agg<true><<<2048, 256, 0, stream>>>(xl, xragg, att + l * 256, gatb + l * 256, rowptr,
                                                  eid, srcv, eattr, src_perm, ea_perm, We + l * 2048);
        else
            k_agg<false><<<2048, 256, 0, stream>>>(xl, xragg, att + l * 256, gatb + l * 256, rowptr,
                                                   eid, srcv, eattr, src_perm, ea_perm, We + l * 2048);
        k_tr<<<(NN + 127) / 128, 128, 0, stream>>>(xragg, trW + l * 16384, trb + l * 64, hbuf, stats + l * 128);
        hin = hbuf;
    }
    k_poolhead<<<NB, 256, 0, stream>>>(hbuf, gateW, bidx, stats + 2 * 128, bng + 128, bnb + 128,
                                       fcv, nrot, W1, b1, W2, b2, W3, b3, W4, b4, out);
}

// Round 7
// 698.586 us; speedup vs baseline: 1.1342x; 1.0803x over previous
//
#include <hip/hip_runtime.h>

#define NN 50000
#define NE 400000
#define NB 128
#define NINF (-__builtin_inff())

__device__ __forceinline__ float dpp_add16(float x) {
    int v = __float_as_int(x);
    x += __int_as_float(__builtin_amdgcn_update_dpp(0, v, 0xB1, 0xF, 0xF, true));  // quad_perm(1,0,3,2)
    v = __float_as_int(x);
    x += __int_as_float(__builtin_amdgcn_update_dpp(0, v, 0x4E, 0xF, 0xF, true));  // quad_perm(2,3,0,1)
    v = __float_as_int(x);
    x += __int_as_float(__builtin_amdgcn_update_dpp(0, v, 0x141, 0xF, 0xF, true)); // row_half_mirror
    v = __float_as_int(x);
    x += __int_as_float(__builtin_amdgcn_update_dpp(0, v, 0x140, 0xF, 0xF, true)); // row_mirror
    return x;
}

// ============================ CSR build ============================
__global__ __launch_bounds__(256) void k_hist(const int* __restrict__ dstv, int* __restrict__ deg) {
    int e = blockIdx.x * 256 + threadIdx.x;
    if (e < NE) atomicAdd(&deg[dstv[e]], 1);
}

__global__ __launch_bounds__(256) void k_scan1(const int* __restrict__ deg, int* __restrict__ bsum) {
    __shared__ int ws[4];
    const int tid = threadIdx.x, lane = tid & 63, w = tid >> 6;
    const int i = blockIdx.x * 256 + tid;
    int v = (i < NN) ? deg[i] : 0;
    #pragma unroll
    for (int off = 32; off; off >>= 1) v += __shfl_xor(v, off);
    if (lane == 0) ws[w] = v;
    __syncthreads();
    if (tid == 0) bsum[blockIdx.x] = ws[0] + ws[1] + ws[2] + ws[3];
}

__global__ __launch_bounds__(256) void k_scan2(const int* __restrict__ bsum, int* __restrict__ boff, int nblk) {
    __shared__ int ws[4];
    const int tid = threadIdx.x, lane = tid & 63, w = tid >> 6;
    int v = (tid < nblk) ? bsum[tid] : 0;
    int incl = v;
    #pragma unroll
    for (int off = 1; off < 64; off <<= 1) {
        int t = __shfl_up(incl, off);
        if (lane >= off) incl += t;
    }
    if (lane == 63) ws[w] = incl;
    __syncthreads();
    int add = 0;
    for (int k = 0; k < w; ++k) add += ws[k];
    if (tid < nblk) boff[tid] = add + incl - v;
}

__global__ __launch_bounds__(256) void k_scan3(const int* __restrict__ deg, const int* __restrict__ boff,
                                               int* __restrict__ rowptr) {
    __shared__ int ws[4];
    const int tid = threadIdx.x, lane = tid & 63, w = tid >> 6;
    const int i = blockIdx.x * 256 + tid;
    int v = (i < NN) ? deg[i] : 0;
    int incl = v;
    #pragma unroll
    for (int off = 1; off < 64; off <<= 1) {
        int t = __shfl_up(incl, off);
        if (lane >= off) incl += t;
    }
    if (lane == 63) ws[w] = incl;
    __syncthreads();
    int add = boff[blockIdx.x];
    for (int k = 0; k < w; ++k) add += ws[k];
    if (i < NN) rowptr[i + 1] = add + incl;
    if (i == 0) rowptr[0] = 0;
}

__global__ __launch_bounds__(256) void k_scatter(const int* __restrict__ dstv, const int* __restrict__ srcv,
                                                 const float* __restrict__ eattr, const int* __restrict__ rowptr,
                                                 int* __restrict__ cnt, int* __restrict__ eid,
                                                 int* __restrict__ src_perm, float4* __restrict__ ea_perm,
                                                 int use_perm) {
    int e = blockIdx.x * 256 + threadIdx.x;
    if (e < NE) {
        int d = dstv[e];
        int pos = rowptr[d] + atomicAdd(&cnt[d], 1);
        eid[pos] = e;
        if (use_perm) {
            src_perm[pos] = srcv[e];
            ea_perm[(size_t)pos * 2] = ((const float4*)eattr)[e * 2];
            ea_perm[(size_t)pos * 2 + 1] = ((const float4*)eattr)[e * 2 + 1];
        }
    }
}

// ============================ GEMM: [N,64] @ [64,256] -> xl / xr ============================
// 128 rows x 128 cols per block; 8x8 microtile; K chunked x2 -> ~34KB LDS -> 4 blocks/CU.
// A staged TRANSPOSED per chunk (broadcast reads, 2.0 FLOP/LDS-byte).
// blockIdx.y: bit0 = col half, bit1 = mat. BN of prev layer folded in-kernel.
__global__ __launch_bounds__(256, 4) void k_gemm64(const float* __restrict__ A, const float* __restrict__ Wl,
                                                   const float* __restrict__ Wr, float* __restrict__ Cl,
                                                   float* __restrict__ Cr, const float* __restrict__ stats,
                                                   const float* __restrict__ bg, const float* __restrict__ bb) {
    __shared__ float At[32 * 132];  // 16,896 B
    __shared__ float Ws[32 * 128];  // 16,384 B
    __shared__ float sc_s[64], sh_s[64], shW_s[128];
    const int tid = threadIdx.x;
    const int mat = blockIdx.y >> 1, ch = blockIdx.y & 1;
    const float* W = mat ? Wr : Wl;
    float* C = mat ? Cr : Cl;
    const int r0b = blockIdx.x * 128;
    const int cg = tid & 15; // cols cg*4..+3 and 64+cg*4..+3
    const int rg = tid >> 4; // rows rg*8..+7

    if (stats) {
        if (tid < 64) {
            const float mu = stats[tid] * (1.0f / (float)NN);
            const float var = stats[64 + tid] * (1.0f / (float)NN) - mu * mu;
            const float rstd = rsqrtf(var + 1e-5f);
            const float sc = bg[tid] * rstd;
            sc_s[tid] = sc;
            sh_s[tid] = fmaf(-mu, sc, bb[tid]);
        }
        __syncthreads();
        if (tid < 128) {
            const float* wc = W + ch * 128 + tid;
            float s = 0.f;
            for (int k = 0; k < 64; ++k) s = fmaf(sh_s[k], wc[k * 256], s);
            shW_s[tid] = s;
        }
        __syncthreads();
    }

    float acc[8][8];
    if (stats) {
        #pragma unroll
        for (int rr = 0; rr < 8; ++rr)
            #pragma unroll
            for (int j = 0; j < 8; ++j)
                acc[rr][j] = (j < 4) ? shW_s[cg * 4 + j] : shW_s[64 + cg * 4 + (j - 4)];
    } else {
        #pragma unroll
        for (int rr = 0; rr < 8; ++rr)
            #pragma unroll
            for (int j = 0; j < 8; ++j) acc[rr][j] = 0.f;
    }

    for (int kc = 0; kc < 2; ++kc) {
        if (kc) __syncthreads();
        // W chunk: rows kc*32..+31 of this col half (scaled if BN)
        for (int i = tid; i < 1024; i += 256) {
            const int k = i >> 5, c4 = i & 31;
            float4 v = ((const float4*)W)[(kc * 32 + k) * 64 + ch * 32 + c4];
            if (stats) {
                const float s = sc_s[kc * 32 + k];
                v.x *= s; v.y *= s; v.z *= s; v.w *= s;
            }
            ((float4*)Ws)[i] = v;
        }
        // A chunk transposed: At[k][r], k in [0,32)
        for (int i = tid; i < 1024; i += 256) {
            const int r = i >> 3, c4 = i & 7;
            const int rgl = (r0b + r < NN) ? (r0b + r) : (NN - 1);
            const float4 v = ((const float4*)A)[rgl * 16 + kc * 8 + c4];
            At[(c4 * 4 + 0) * 132 + r] = v.x;
            At[(c4 * 4 + 1) * 132 + r] = v.y;
            At[(c4 * 4 + 2) * 132 + r] = v.z;
            At[(c4 * 4 + 3) * 132 + r] = v.w;
        }
        __syncthreads();
        #pragma unroll 4
        for (int k = 0; k < 32; ++k) {
            const float4 a0 = *(const float4*)(At + k * 132 + rg * 8);
            const float4 a1 = *(const float4*)(At + k * 132 + rg * 8 + 4);
            const float4 w0 = *(const float4*)(Ws + k * 128 + cg * 4);
            const float4 w1 = *(const float4*)(Ws + k * 128 + 64 + cg * 4);
            const float ar[8] = {a0.x, a0.y, a0.z, a0.w, a1.x, a1.y, a1.z, a1.w};
            #pragma unroll
            for (int rr = 0; rr < 8; ++rr) {
                acc[rr][0] = fmaf(ar[rr], w0.x, acc[rr][0]);
                acc[rr][1] = fmaf(ar[rr], w0.y, acc[rr][1]);
                acc[rr][2] = fmaf(ar[rr], w0.z, acc[rr][2]);
                acc[rr][3] = fmaf(ar[rr], w0.w, acc[rr][3]);
                acc[rr][4] = fmaf(ar[rr], w1.x, acc[rr][4]);
                acc[rr][5] = fmaf(ar[rr], w1.y, acc[rr][5]);
                acc[rr][6] = fmaf(ar[rr], w1.z, acc[rr][6]);
                acc[rr][7] = fmaf(ar[rr], w1.w, acc[rr][7]);
            }
        }
    }
    #pragma unroll
    for (int rr = 0; rr < 8; ++rr) {
        const int r = r0b + rg * 8 + rr;
        if (r < NN) {
            float* cp = C + (size_t)r * 256 + ch * 128 + cg * 4;
            *(float4*)cp = make_float4(acc[rr][0], acc[rr][1], acc[rr][2], acc[rr][3]);
            *(float4*)(cp + 64) = make_float4(acc[rr][4], acc[rr][5], acc[rr][6], acc[rr][7]);
        }
    }
}

// ============================ Fused edge kernel ============================
// wave per node; lane L owns channels 4L..4L+3; We in 32 regs; 3-slot gather pipeline;
// no-max softmax; DPP row reduce.
template <bool PERM>
__global__ __launch_bounds__(256, 4) void k_agg(const float* __restrict__ xl, float* __restrict__ xragg,
                                                const float* __restrict__ att, const float* __restrict__ gatb,
                                                const int* __restrict__ rowptr, const int* __restrict__ eid,
                                                const int* __restrict__ srcv, const float* __restrict__ eattr,
                                                const int* __restrict__ src_perm, const float4* __restrict__ ea_perm,
                                                const float* __restrict__ We) {
    const int lane = threadIdx.x & 63;
    const float4 we0 = ((const float4*)(We + 0 * 256))[lane];
    const float4 we1 = ((const float4*)(We + 1 * 256))[lane];
    const float4 we2 = ((const float4*)(We + 2 * 256))[lane];
    const float4 we3 = ((const float4*)(We + 3 * 256))[lane];
    const float4 we4 = ((const float4*)(We + 4 * 256))[lane];
    const float4 we5 = ((const float4*)(We + 5 * 256))[lane];
    const float4 we6 = ((const float4*)(We + 6 * 256))[lane];
    const float4 we7 = ((const float4*)(We + 7 * 256))[lane];
    const float4 attf = ((const float4*)att)[lane];
    const float4 gbf = ((const float4*)gatb)[lane];
    const int nw = gridDim.x * (blockDim.x >> 6);
    int wid = blockIdx.x * (blockDim.x >> 6) + (threadIdx.x >> 6);

#define LOADE(X, idx)                                                          \
    {                                                                          \
        int s_;                                                                \
        const float4* eap_;                                                    \
        if (PERM) {                                                            \
            s_ = src_perm[idx];                                                \
            eap_ = ea_perm + (size_t)(idx) * 2;                                \
        } else {                                                               \
            const int e_ = eid[idx];                                           \
            s_ = srcv[e_];                                                     \
            eap_ = (const float4*)(eattr + (size_t)e_ * 8);                    \
        }                                                                      \
        X##x = ((const float4*)(xl + (size_t)s_ * 256))[lane];                 \
        X##a = eap_[0];                                                        \
        X##b = eap_[1];                                                        \
    }

#define PROC(X)                                                                \
    {                                                                          \
        float v0 = fmaf(X##a.x, we0.x, xr.x), v1 = fmaf(X##a.x, we0.y, xr.y);  \
        float v2 = fmaf(X##a.x, we0.z, xr.z), v3 = fmaf(X##a.x, we0.w, xr.w);  \
        v0 = fmaf(X##a.y, we1.x, v0); v1 = fmaf(X##a.y, we1.y, v1);            \
        v2 = fmaf(X##a.y, we1.z, v2); v3 = fmaf(X##a.y, we1.w, v3);            \
        v0 = fmaf(X##a.z, we2.x, v0); v1 = fmaf(X##a.z, we2.y, v1);            \
        v2 = fmaf(X##a.z, we2.z, v2); v3 = fmaf(X##a.z, we2.w, v3);            \
        v0 = fmaf(X##a.w, we3.x, v0); v1 = fmaf(X##a.w, we3.y, v1);            \
        v2 = fmaf(X##a.w, we3.z, v2); v3 = fmaf(X##a.w, we3.w, v3);            \
        v0 = fmaf(X##b.x, we4.x, v0); v1 = fmaf(X##b.x, we4.y, v1);            \
        v2 = fmaf(X##b.x, we4.z, v2); v3 = fmaf(X##b.x, we4.w, v3);            \
        v0 = fmaf(X##b.y, we5.x, v0); v1 = fmaf(X##b.y, we5.y, v1);            \
        v2 = fmaf(X##b.y, we5.z, v2); v3 = fmaf(X##b.y, we5.w, v3);            \
        v0 = fmaf(X##b.z, we6.x, v0); v1 = fmaf(X##b.z, we6.y, v1);            \
        v2 = fmaf(X##b.z, we6.z, v2); v3 = fmaf(X##b.z, we6.w, v3);            \
        v0 = fmaf(X##b.w, we7.x, v0); v1 = fmaf(X##b.w, we7.y, v1);            \
        v2 = fmaf(X##b.w, we7.z, v2); v3 = fmaf(X##b.w, we7.w, v3);            \
        v0 += X##x.x; v1 += X##x.y; v2 += X##x.z; v3 += X##x.w;                \
        v0 = fmaxf(v0, 0.2f * v0); v1 = fmaxf(v1, 0.2f * v1);                  \
        v2 = fmaxf(v2, 0.2f * v2); v3 = fmaxf(v3, 0.2f * v3);                  \
        float part = v0 * attf.x;                                              \
        part = fmaf(v1, attf.y, part);                                         \
        part = fmaf(v2, attf.z, part);                                         \
        part = fmaf(v3, attf.w, part);                                         \
        part = dpp_add16(part);                                                \
        const float p = __expf(part);                                          \
        den += p;                                                              \
        c0 = fmaf(p, X##x.x, c0);                                              \
        c1 = fmaf(p, X##x.y, c1);                                              \
        c2 = fmaf(p, X##x.z, c2);                                              \
        c3 = fmaf(p, X##x.w, c3);                                              \
    }

    for (int n = wid; n < NN; n += nw) {
        const int e0 = rowptr[n], e1 = rowptr[n + 1];
        const float4 xr = ((const float4*)(xragg + (size_t)n * 256))[lane];
        float den = 0.f, c0 = 0.f, c1 = 0.f, c2 = 0.f, c3 = 0.f;
        float4 Ax, Aa, Ab, Bx, Ba, Bb, Cx, Ca, Cb;
        const int cnt = e1 - e0;
        if (cnt > 0) {
            LOADE(A, e0);
            if (cnt > 1) LOADE(B, e0 + 1);
            if (cnt > 2) LOADE(C, e0 + 2);
            int i = e0;
            for (; i + 5 < e1; i += 3) {
                PROC(A);
                LOADE(A, i + 3);
                PROC(B);
                LOADE(B, i + 4);
                PROC(C);
                LOADE(C, i + 5);
            }
            const int m = e1 - i; // 1..5
            PROC(A);
            if (m >= 2) PROC(B);
            if (m >= 3) PROC(C);
            if (m >= 4) { LOADE(A, i + 3); PROC(A); }
            if (m == 5) { LOADE(B, i + 4); PROC(B); }
        }
        float4 o;
        if (cnt > 0) {
            const float inv = 1.0f / den;
            o.x = fmaf(c0, inv, gbf.x);
            o.y = fmaf(c1, inv, gbf.y);
            o.z = fmaf(c2, inv, gbf.z);
            o.w = fmaf(c3, inv, gbf.w);
        } else {
            o = gbf;
        }
        ((float4*)(xragg + (size_t)n * 256))[lane] = o;
    }
#undef LOADE
#undef PROC
}

// ============================ tr GEMM: [N,256]@[256,64] + bias, relu, BN stats ============================
// 256 rows x 64 cols per block, 256 threads, 8x8 microtile; K chunked x8 (~42KB LDS, 3 blocks/CU).
__global__ __launch_bounds__(256, 4) void k_tr(const float* __restrict__ A, const float* __restrict__ W,
                                               const float* __restrict__ bias, float* __restrict__ Hout,
                                               float* __restrict__ stats) {
    __shared__ float At[32 * 260]; // 33,280 B (transposed chunk, pad 260)
    __shared__ float Ws[32 * 64];  // 8,192 B
    __shared__ float red[128];
    const int tid = threadIdx.x;
    const int cg = tid & 7;  // cols cg*8..+7
    const int rg = tid >> 3; // rows rg*8..+7 (0..31)
    const int r0b = blockIdx.x * 256;

    float acc[8][8];
    #pragma unroll
    for (int rr = 0; rr < 8; ++rr)
        #pragma unroll
        for (int j = 0; j < 8; ++j)
            acc[rr][j] = bias[cg * 8 + j];

    for (int kc = 0; kc < 8; ++kc) {
        if (kc) __syncthreads();
        for (int i = tid; i < 512; i += 256)
            ((float4*)Ws)[i] = ((const float4*)(W + kc * 2048))[i];
        for (int i = tid; i < 2048; i += 256) {
            const int r = i >> 3, c4 = i & 7;
            const int rgl = (r0b + r < NN) ? (r0b + r) : (NN - 1);
            const float4 v = ((const float4*)A)[(size_t)rgl * 64 + kc * 8 + c4];
            At[(c4 * 4 + 0) * 260 + r] = v.x;
            At[(c4 * 4 + 1) * 260 + r] = v.y;
            At[(c4 * 4 + 2) * 260 + r] = v.z;
            At[(c4 * 4 + 3) * 260 + r] = v.w;
        }
        __syncthreads();
        #pragma unroll 4
        for (int k = 0; k < 32; ++k) {
            const float4 a0 = *(const float4*)(At + k * 260 + rg * 8);
            const float4 a1 = *(const float4*)(At + k * 260 + rg * 8 + 4);
            const float4 w0 = *(const float4*)(Ws + k * 64 + cg * 8);
            const float4 w1 = *(const float4*)(Ws + k * 64 + cg * 8 + 4);
            const float ar[8] = {a0.x, a0.y, a0.z, a0.w, a1.x, a1.y, a1.z, a1.w};
            #pragma unroll
            for (int rr = 0; rr < 8; ++rr) {
                acc[rr][0] = fmaf(ar[rr], w0.x, acc[rr][0]);
                acc[rr][1] = fmaf(ar[rr], w0.y, acc[rr][1]);
                acc[rr][2] = fmaf(ar[rr], w0.z, acc[rr][2]);
                acc[rr][3] = fmaf(ar[rr], w0.w, acc[rr][3]);
                acc[rr][4] = fmaf(ar[rr], w1.x, acc[rr][4]);
                acc[rr][5] = fmaf(ar[rr], w1.y, acc[rr][5]);
                acc[rr][6] = fmaf(ar[rr], w1.z, acc[rr][6]);
                acc[rr][7] = fmaf(ar[rr], w1.w, acc[rr][7]);
            }
        }
    }
    float lsum[8], lsq[8];
    #pragma unroll
    for (int j = 0; j < 8; ++j) { lsum[j] = 0.f; lsq[j] = 0.f; }
    #pragma unroll
    for (int rr = 0; rr < 8; ++rr) {
        const int r = r0b + rg * 8 + rr;
        if (r < NN) {
            float v[8];
            #pragma unroll
            for (int j = 0; j < 8; ++j) {
                v[j] = fmaxf(acc[rr][j], 0.f);
                lsum[j] += v[j];
                lsq[j] = fmaf(v[j], v[j], lsq[j]);
            }
            float* hp = Hout + (size_t)r * 64;
            *(float4*)(hp + cg * 8) = make_float4(v[0], v[1], v[2], v[3]);
            *(float4*)(hp + cg * 8 + 4) = make_float4(v[4], v[5], v[6], v[7]);
        }
    }
    __syncthreads();
    if (tid < 128) red[tid] = 0.f;
    __syncthreads();
    #pragma unroll
    for (int j = 0; j < 8; ++j) {
        atomicAdd(&red[cg * 8 + j], lsum[j]);
        atomicAdd(&red[64 + cg * 8 + j], lsq[j]);
    }
    __syncthreads();
    if (tid < 64) {
        atomicAdd(&stats[tid], red[tid]);
        atomicAdd(&stats[64 + tid], red[64 + tid]);
    }
}

// ============================ fused gate + pool + BN fold + MLP head ============================
__global__ __launch_bounds__(256) void k_poolhead(const float* __restrict__ h, const float* __restrict__ gw,
                                                  const int* __restrict__ bidx, const float* __restrict__ stats,
                                                  const float* __restrict__ bg, const float* __restrict__ bb,
                                                  const float* __restrict__ fc, const float* __restrict__ nrot,
                                                  const float* __restrict__ W1, const float* __restrict__ b1,
                                                  const float* __restrict__ W2, const float* __restrict__ b2,
                                                  const float* __restrict__ W3, const float* __restrict__ b3,
                                                  const float* __restrict__ W4, const float* __restrict__ b4,
                                                  float* __restrict__ out) {
    __shared__ float gate_s[1024];
    __shared__ float red[4];
    __shared__ float pp[4][64];
    __shared__ float scb[64], shb[64];
    __shared__ float z[66], a1[256], a2[128], a3[64];
    const int b = blockIdx.x, tid = threadIdx.x, lane = tid & 63, w = tid >> 6;
    if (tid < 64) {
        const float mu = stats[tid] * (1.0f / (float)NN);
        const float var = stats[64 + tid] * (1.0f / (float)NN) - mu * mu;
        const float rstd = rsqrtf(var + 1e-5f);
        const float sc = bg[tid] * rstd;
        scb[tid] = sc;
        shb[tid] = fmaf(-mu, sc, bb[tid]);
    }
    int lo = 0, hi = NN;
    while (lo < hi) { int mid = (lo + hi) >> 1; if (bidx[mid] < b) lo = mid + 1; else hi = mid; }
    const int s0 = lo;
    lo = 0; hi = NN;
    while (lo < hi) { int mid = (lo + hi) >> 1; if (bidx[mid] < b + 1) lo = mid + 1; else hi = mid; }
    const int s1 = lo;
    const int seg = s1 - s0;
    __syncthreads();

    const float gwv = gw[lane] * scb[lane];
    for (int i = s0 + w; i < s1; i += 4) {
        float p = h[(size_t)i * 64 + lane] * gwv;
        #pragma unroll
        for (int off = 32; off; off >>= 1) p += __shfl_xor(p, off);
        if (lane == 0) gate_s[i - s0] = p;
    }
    __syncthreads();
    float v = NINF;
    for (int i = tid; i < seg; i += 256) v = fmaxf(v, gate_s[i]);
    #pragma unroll
    for (int off = 32; off; off >>= 1) v = fmaxf(v, __shfl_xor(v, off));
    if (lane == 0) red[w] = v;
    __syncthreads();
    const float mx = fmaxf(fmaxf(red[0], red[1]), fmaxf(red[2], red[3]));
    __syncthreads();
    float d = 0.f;
    for (int i = tid; i < seg; i += 256) {
        const float ex = __expf(gate_s[i] - mx);
        gate_s[i] = ex;
        d += ex;
    }
    #pragma unroll
    for (int off = 32; off; off >>= 1) d += __shfl_xor(d, off);
    if (lane == 0) red[w] = d;
    __syncthreads();
    const float den = red[0] + red[1] + red[2] + red[3];
    const int c = tid & 63, ro = tid >> 6;
    float acc = 0.f;
    for (int i = s0 + ro; i < s1; i += 4) acc = fmaf(gate_s[i - s0], h[(size_t)i * 64 + c], acc);
    pp[ro][c] = acc;
    __syncthreads();
    if (tid < 64) {
        const float raw = (pp[0][tid] + pp[1][tid] + pp[2][tid] + pp[3][tid]) / den;
        z[tid] = (seg > 0) ? fmaf(raw, scb[tid], shb[tid]) : shb[tid];
    }
    if (tid == 64) z[64] = fc[b];
    if (tid == 65) z[65] = nrot[b];
    __syncthreads();
    float s = b1[tid];
    for (int k = 0; k < 66; ++k) s = fmaf(z[k], W1[k * 256 + tid], s);
    a1[tid] = fmaxf(s, 0.f);
    __syncthreads();
    if (tid < 128) {
        float s2 = b2[tid];
        for (int k = 0; k < 256; ++k) s2 = fmaf(a1[k], W2[k * 128 + tid], s2);
        a2[tid] = fmaxf(s2, 0.f);
    }
    __syncthreads();
    if (tid < 64) {
        float s3 = b3[tid];
        for (int k = 0; k < 128; ++k) s3 = fmaf(a2[k], W3[k * 64 + tid], s3);
        a3[tid] = fmaxf(s3, 0.f);
    }
    __syncthreads();
    if (tid < 64) {
        float p = a3[tid] * W4[tid];
        #pragma unroll
        for (int off = 32; off; off >>= 1) p += __shfl_xor(p, off);
        if (tid == 0) out[b] = p + b4[0];
    }
}

// ============================ launch ============================
extern "C" void kernel_launch(void* const* d_in, const int* in_sizes, int n_in,
                              void* d_out, int out_size, void* d_ws, size_t ws_size,
                              hipStream_t stream) {
    const float* x     = (const float*)d_in[0];
    const int*   ei    = (const int*)d_in[1];
    const float* eattr = (const float*)d_in[2];
    const float* fcv   = (const float*)d_in[3];
    const float* nrot  = (const float*)d_in[4];
    const int*   bidx  = (const int*)d_in[5];
    const float* Wl    = (const float*)d_in[6];
    const float* Wr    = (const float*)d_in[7];
    const float* We    = (const float*)d_in[8];
    const float* att   = (const float*)d_in[9];
    const float* gatb  = (const float*)d_in[10];
    const float* trW   = (const float*)d_in[11];
    const float* trb   = (const float*)d_in[12];
    const float* bng   = (const float*)d_in[13];
    const float* bnb   = (const float*)d_in[14];
    const float* gateW = (const float*)d_in[15];
    const float* W1    = (const float*)d_in[17];
    const float* b1    = (const float*)d_in[18];
    const float* W2    = (const float*)d_in[19];
    const float* b2    = (const float*)d_in[20];
    const float* W3    = (const float*)d_in[21];
    const float* b3    = (const float*)d_in[22];
    const float* W4    = (const float*)d_in[23];
    const float* b4    = (const float*)d_in[24];
    float* out = (float*)d_out;

    const int* srcv = ei;
    const int* dstv = ei + NE;

    char* w = (char*)d_ws;
    float*  xl       = (float*)(w);                 // 51,200,000
    float*  xragg    = (float*)(w + 51200000);      // 51,200,000 (xr in, agg out)
    float*  hbuf     = (float*)(w + 102400000);     // 12,800,000
    int*    deg      = (int*)  (w + 102400000);     // overlaps hbuf (dead before first k_tr)
    int*    cnt      = (int*)  (w + 102600000);     // overlaps hbuf
    int*    eid      = (int*)  (w + 115200000);     // 1,600,000
    int*    rowptr   = (int*)  (w + 116800000);     // 200,004
    float*  stats    = (float*)(w + 117000064);     // 1,536 (3 * 128 * 4)
    int*    bsum     = (int*)  (w + 117004096);     // 784
    int*    boff     = (int*)  (w + 117006144);     // 784
    int*    src_perm = (int*)  (w + 117042048);     // 1,600,000
    float4* ea_perm  = (float4*)(w + 118642048);    // 12,800,000 -> 131,442,048
    const bool use_perm = (ws_size >= (size_t)131442048);
    const int NBLK = (NN + 255) / 256; // 196

    hipMemsetAsync(deg, 0, 400000, stream);         // deg + cnt
    hipMemsetAsync(stats, 0, 1536, stream);
    k_hist<<<(NE + 255) / 256, 256, 0, stream>>>(dstv, deg);
    k_scan1<<<NBLK, 256, 0, stream>>>(deg, bsum);
    k_scan2<<<1, 256, 0, stream>>>(bsum, boff, NBLK);
    k_scan3<<<NBLK, 256, 0, stream>>>(deg, boff, rowptr);
    k_scatter<<<(NE + 255) / 256, 256, 0, stream>>>(dstv, srcv, eattr, rowptr, cnt, eid,
                                                    src_perm, ea_perm, use_perm ? 1 : 0);

    const float* hin = x;
    for (int l = 0; l < 3; ++l) {
        const float* st = (l == 0) ? nullptr : (stats + (l - 1) * 128);
        const float* g  = (l == 0) ? nullptr : (bng + (l - 1) * 64);
        const float* bb = (l == 0) ? nullptr : (bnb + (l - 1) * 64);
        dim3 gg((NN + 127) / 128, 4);
        k_gemm64<<<gg, 256, 0, stream>>>(hin, Wl + l * 16384, Wr + l * 16384, xl, xragg, st, g, bb);
        if (use_perm)
            k_agg<true><<<2048, 256, 0, stream>>>(xl, xragg, att + l * 256, gatb + l * 256, rowptr,
                                                  eid, srcv, eattr, src_perm, ea_perm, We + l * 2048);
        else
            k_agg<false><<<2048, 256, 0, stream>>>(xl, xragg, att + l * 256, gatb + l * 256, rowptr,
                                                   eid, srcv, eattr, src_perm, ea_perm, We + l * 2048);
        k_tr<<<(NN + 255) / 256, 256, 0, stream>>>(xragg, trW + l * 16384, trb + l * 64, hbuf, stats + l * 128);
        hin = hbuf;
    }
    k_poolhead<<<NB, 256, 0, stream>>>(hbuf, gateW, bidx, stats + 2 * 128, bng + 128, bnb + 128,
                                       fcv, nrot, W1, b1, W2, b2, W3, b3, W4, b4, out);
}